// Round 2
// baseline (2522.683 us; speedup 1.0000x reference)
//
#include <hip/hip_runtime.h>
#include <math.h>

#define B_    2
#define S_    4096
#define D_    1024
#define H_    16
#define DH_   64
#define NH_   4
#define BS_   64
#define C_    64
#define BSD_  8388608     // B*S*D
#define ROWS_ 131072      // B*H*S
#define SCALE_ 0.125f     // DH^-0.5

__device__ __forceinline__ float sigf(float x) { return 1.f / (1.f + expf(-x)); }

// ---------------------------------------------------------------------------
// fp32 GEMM: C(8192x1024) = A(8192x1024) @ W(1024x1024), 128x128 tile,
// 256 threads, 8x8 microtile.
// MODE 0: A flat (B*S, D);    out head-layout [((b*H+h)*S+s)*64+dh]
// MODE 1: A head-layout;      out = resid + sigmoid(gate[n]) * acc      (y1)
// MODE 2: A flat;             out = relu(acc + bias[n])                 (ffn1)
// MODE 3: A flat;             out = resid + sigmoid(gate[n])*(acc+bias) (y2)
// ---------------------------------------------------------------------------
template<int MODE>
__global__ __launch_bounds__(256)
void gemm_f32(const float* __restrict__ A, const float* __restrict__ W,
              float* __restrict__ out, const float* __restrict__ bias,
              const float* __restrict__ resid, const float* __restrict__ gatev) {
    const int K = 1024, N = 1024;
    __shared__ float As[16][129];   // transposed: As[k][m]
    __shared__ float Bs[16][128];
    const int tid = threadIdx.x;
    const int ty = tid >> 4, tx = tid & 15;
    const int m0 = blockIdx.y * 128, n0 = blockIdx.x * 128;

    float acc[8][8];
#pragma unroll
    for (int i = 0; i < 8; ++i)
#pragma unroll
        for (int j = 0; j < 8; ++j) acc[i][j] = 0.f;

    for (int kt = 0; kt < K; kt += 16) {
#pragma unroll
        for (int l = 0; l < 2; ++l) {
            int cid = tid + l * 256;                 // 0..511
            int r  = cid >> 2, c4 = (cid & 3) << 2;  // A chunk
            float4 a4;
            if (MODE == 1) {
                int k = kt + c4;
                int hh = k >> 6, dd = k & 63;        // k%64 stays in-head for c4..c4+3
                int m = m0 + r, bb = m >> 12, s = m & 4095;
                a4 = *reinterpret_cast<const float4*>(
                    &A[((((size_t)bb * H_ + hh) * S_ + s) << 6) + dd]);
            } else {
                a4 = *reinterpret_cast<const float4*>(&A[(size_t)(m0 + r) * K + kt + c4]);
            }
            As[c4 + 0][r] = a4.x; As[c4 + 1][r] = a4.y;
            As[c4 + 2][r] = a4.z; As[c4 + 3][r] = a4.w;
            int r2 = cid >> 5, c42 = (cid & 31) << 2; // B chunk
            *reinterpret_cast<float4*>(&Bs[r2][c42]) =
                *reinterpret_cast<const float4*>(&W[(size_t)(kt + r2) * N + n0 + c42]);
        }
        __syncthreads();
#pragma unroll
        for (int kk = 0; kk < 16; ++kk) {
            float a[8], b[8];
#pragma unroll
            for (int i = 0; i < 8; ++i) a[i] = As[kk][ty * 8 + i];
            float4 b0 = *reinterpret_cast<float4*>(&Bs[kk][tx * 8]);
            float4 b1 = *reinterpret_cast<float4*>(&Bs[kk][tx * 8 + 4]);
            b[0] = b0.x; b[1] = b0.y; b[2] = b0.z; b[3] = b0.w;
            b[4] = b1.x; b[5] = b1.y; b[6] = b1.z; b[7] = b1.w;
#pragma unroll
            for (int i = 0; i < 8; ++i)
#pragma unroll
                for (int j = 0; j < 8; ++j) acc[i][j] += a[i] * b[j];
        }
        __syncthreads();
    }

#pragma unroll
    for (int i = 0; i < 8; ++i) {
        int m = m0 + ty * 8 + i;
        if (MODE == 0) {
            int bb = m >> 12, s = m & 4095;
            int n = n0 + tx * 8;
            int h = n >> 6, dh = n & 63;
            float* op = out + ((((size_t)bb * H_ + h) * S_ + s) << 6) + dh;
            *reinterpret_cast<float4*>(op)     = make_float4(acc[i][0], acc[i][1], acc[i][2], acc[i][3]);
            *reinterpret_cast<float4*>(op + 4) = make_float4(acc[i][4], acc[i][5], acc[i][6], acc[i][7]);
        } else {
            size_t base = (size_t)m * 1024 + n0 + tx * 8;
            float vals[8];
#pragma unroll
            for (int j = 0; j < 8; ++j) {
                float v = acc[i][j];
                int n = n0 + tx * 8 + j;
                if (MODE == 2) v = fmaxf(v + bias[n], 0.f);
                if (MODE == 1) v = resid[base + j] + sigf(gatev[n]) * v;
                if (MODE == 3) v = resid[base + j] + sigf(gatev[n]) * (v + bias[n]);
                vals[j] = v;
            }
            *reinterpret_cast<float4*>(&out[base])     = make_float4(vals[0], vals[1], vals[2], vals[3]);
            *reinterpret_cast<float4*>(&out[base + 4]) = make_float4(vals[4], vals[5], vals[6], vals[7]);
        }
    }
}

// ---------------------------------------------------------------------------
// rnorm[row] = 1/(||qk_row|| + 1e-6), wave per row
// ---------------------------------------------------------------------------
__global__ __launch_bounds__(256)
void rnorm_kernel(const float* __restrict__ qk, float* __restrict__ rnorm) {
    int tid = threadIdx.x, wv = tid >> 6, lane = tid & 63;
    int row = blockIdx.x * 4 + wv;
    float q = qk[(size_t)row * 64 + lane];
    float ss = q * q;
#pragma unroll
    for (int off = 32; off; off >>= 1) ss += __shfl_xor(ss, off);
    if (lane == 0) rnorm[row] = 1.f / (sqrtf(ss) + 1e-6f);
}

// ---------------------------------------------------------------------------
// buckets: rotd[m] = sum_d qk[d]*rot[h][r][d][m]; argmax over [rotd,-rotd]
// ---------------------------------------------------------------------------
__global__ __launch_bounds__(256)
void buckets_kernel(const float* __restrict__ qk, const float* __restrict__ rot,
                    int* __restrict__ buckets) {
    int g = blockIdx.y;                  // (b*H+h)*4 + r
    int tok = blockIdx.x * 256 + threadIdx.x;
    int r = g & 3;
    int bh = g >> 2;
    int h = bh & 15;
    const float* qrow = qk + ((size_t)bh * S_ + tok) * 64;
    const float* rbase = rot + (size_t)(h * NH_ + r) * 64 * 32;

    float rotd[32];
#pragma unroll
    for (int m = 0; m < 32; ++m) rotd[m] = 0.f;
#pragma unroll
    for (int d4 = 0; d4 < 16; ++d4) {
        float4 q4 = *reinterpret_cast<const float4*>(qrow + (d4 << 2));
        const float* rp = rbase + (d4 << 2) * 32;
#pragma unroll
        for (int m = 0; m < 32; ++m)
            rotd[m] += q4.x * rp[m] + q4.y * rp[32 + m] + q4.z * rp[64 + m] + q4.w * rp[96 + m];
    }
    float bv = rotd[0]; int bi = 0;
#pragma unroll
    for (int m = 1; m < 32; ++m) if (rotd[m] > bv) { bv = rotd[m]; bi = m; }
#pragma unroll
    for (int m = 0; m < 32; ++m) { float nv = -rotd[m]; if (nv > bv) { bv = nv; bi = 32 + m; } }
    buckets[(size_t)g * S_ + tok] = bi;
}

// ---------------------------------------------------------------------------
// Stable counting sort per group g: perm = argsort(bucket*S + pos)
// ---------------------------------------------------------------------------
__global__ __launch_bounds__(256)
void sort_kernel(const int* __restrict__ buckets, int* __restrict__ perm) {
    __shared__ int bk[4096];
    __shared__ int qcnt[4][64];
    __shared__ int qoff[4][64];
    __shared__ int ps[4096];
    int g = blockIdx.x, tid = threadIdx.x;
    const int* bp = buckets + (size_t)g * S_;
    for (int i = 0; i < 16; ++i) bk[tid + 256 * i] = bp[tid + 256 * i];
    qcnt[tid >> 6][tid & 63] = 0;
    __syncthreads();
    int q = tid >> 6, l = tid & 63;
    for (int i = 0; i < 16; ++i) {
        int pos = q * 1024 + l + 64 * i;
        atomicAdd(&qcnt[q][bk[pos]], 1);
    }
    __syncthreads();
    if (tid == 0) {
        int run = 0;
        for (int b = 0; b < 64; ++b)
            for (int qq = 0; qq < 4; ++qq) { qoff[qq][b] = run; run += qcnt[qq][b]; }
    }
    __syncthreads();
    {
        int base = qoff[q][l], cnt = 0;
        for (int j = q * 1024; j < q * 1024 + 1024; ++j) {
            if (bk[j] == l) { ps[base + cnt] = j; ++cnt; }
        }
    }
    __syncthreads();
    int* pp = perm + (size_t)g * S_;
    for (int i = 0; i < 16; ++i) pp[tid + 256 * i] = ps[tid + 256 * i];
}

// ---------------------------------------------------------------------------
// Attention pass 1: per (g, chunk) compute dots(64x128), write per-token lse.
// Block = 128 threads, 8x8 microtile per thread (ty rows, tx cols of 16).
// ---------------------------------------------------------------------------
__global__ __launch_bounds__(128)
void lse_kernel(const float* __restrict__ qk, const float* __restrict__ rnorm,
                const int* __restrict__ perm, float* __restrict__ lseg) {
    __shared__ float sq[64][65];
    __shared__ float sk[128][65];
    __shared__ int toks[128];
    int g = blockIdx.y, c = blockIdx.x, tid = threadIdx.x;
    int bh = g >> 2;
    int pc = (c + 63) & 63;
    toks[tid] = (tid < 64) ? perm[(size_t)g * S_ + c * 64 + tid]
                           : perm[(size_t)g * S_ + pc * 64 + (tid - 64)];
    __syncthreads();
    for (int i = 0; i < 8; ++i) {                       // queries (scaled)
        int cid = tid + 128 * i;
        int row = cid >> 4, c4 = (cid & 15) << 2;
        int t = toks[row];
        float4 v4 = *reinterpret_cast<const float4*>(&qk[((size_t)bh * S_ + t) * 64 + c4]);
        sq[row][c4] = v4.x * SCALE_; sq[row][c4 + 1] = v4.y * SCALE_;
        sq[row][c4 + 2] = v4.z * SCALE_; sq[row][c4 + 3] = v4.w * SCALE_;
    }
    for (int i = 0; i < 16; ++i) {                      // keys (normalized)
        int cid = tid + 128 * i;
        int row = cid >> 4, c4 = (cid & 15) << 2;
        int t = toks[row];
        float rn = rnorm[(size_t)bh * S_ + t];
        float4 v4 = *reinterpret_cast<const float4*>(&qk[((size_t)bh * S_ + t) * 64 + c4]);
        sk[row][c4] = v4.x * rn; sk[row][c4 + 1] = v4.y * rn;
        sk[row][c4 + 2] = v4.z * rn; sk[row][c4 + 3] = v4.w * rn;
    }
    __syncthreads();
    int ty = tid >> 4, tx = tid & 15;
    float acc[8][8];
#pragma unroll
    for (int i = 0; i < 8; ++i)
#pragma unroll
        for (int j = 0; j < 8; ++j) acc[i][j] = 0.f;
    for (int d = 0; d < 64; ++d) {
        float a[8], b[8];
#pragma unroll
        for (int wi = 0; wi < 8; ++wi) a[wi] = sq[ty * 8 + wi][d];
#pragma unroll
        for (int ji = 0; ji < 8; ++ji) b[ji] = sk[ji * 16 + tx][d];
#pragma unroll
        for (int wi = 0; wi < 8; ++wi)
#pragma unroll
            for (int ji = 0; ji < 8; ++ji) acc[wi][ji] += a[wi] * b[ji];
    }
#pragma unroll
    for (int wi = 0; wi < 8; ++wi) {
        float mx = acc[wi][0];
#pragma unroll
        for (int ji = 1; ji < 8; ++ji) mx = fmaxf(mx, acc[wi][ji]);
#pragma unroll
        for (int off = 8; off; off >>= 1) mx = fmaxf(mx, __shfl_xor(mx, off));
        float sm = 0.f;
#pragma unroll
        for (int ji = 0; ji < 8; ++ji) sm += expf(acc[wi][ji] - mx);
#pragma unroll
        for (int off = 8; off; off >>= 1) sm += __shfl_xor(sm, off);
        if (tx == 0) lseg[(size_t)g * S_ + toks[ty * 8 + wi]] = mx + logf(sm);
    }
}

// ---------------------------------------------------------------------------
// Attention pass 2: recompute dots, p = exp(dots - lse), o = p@V, accumulate
// round-softmax-weighted o into lsh (atomic). P gets a full [64][130] buffer
// (reuses q-staging LDS after a barrier) -- fixes round-1 LDS OOB.
// ---------------------------------------------------------------------------
__global__ __launch_bounds__(128)
void pv_kernel(const float* __restrict__ qk, const float* __restrict__ rnorm,
               const float* __restrict__ vg, const int* __restrict__ perm,
               const float* __restrict__ lseg, float* __restrict__ lsh) {
    __shared__ float sqp[64][130];   // q staging (cols 0..63), then P (cols 0..127)
    __shared__ float skv[128][65];   // K staging, then V
    __shared__ int toks[128];
    int g = blockIdx.y, c = blockIdx.x, tid = threadIdx.x;
    int bh = g >> 2, r = g & 3;
    int pc = (c + 63) & 63;
    toks[tid] = (tid < 64) ? perm[(size_t)g * S_ + c * 64 + tid]
                           : perm[(size_t)g * S_ + pc * 64 + (tid - 64)];
    __syncthreads();
    for (int i = 0; i < 8; ++i) {
        int cid = tid + 128 * i;
        int row = cid >> 4, c4 = (cid & 15) << 2;
        int t = toks[row];
        float4 v4 = *reinterpret_cast<const float4*>(&qk[((size_t)bh * S_ + t) * 64 + c4]);
        sqp[row][c4] = v4.x * SCALE_; sqp[row][c4 + 1] = v4.y * SCALE_;
        sqp[row][c4 + 2] = v4.z * SCALE_; sqp[row][c4 + 3] = v4.w * SCALE_;
    }
    for (int i = 0; i < 16; ++i) {
        int cid = tid + 128 * i;
        int row = cid >> 4, c4 = (cid & 15) << 2;
        int t = toks[row];
        float rn = rnorm[(size_t)bh * S_ + t];
        float4 v4 = *reinterpret_cast<const float4*>(&qk[((size_t)bh * S_ + t) * 64 + c4]);
        skv[row][c4] = v4.x * rn; skv[row][c4 + 1] = v4.y * rn;
        skv[row][c4 + 2] = v4.z * rn; skv[row][c4 + 3] = v4.w * rn;
    }
    __syncthreads();
    int ty = tid >> 4, tx = tid & 15;
    float acc[8][8];
#pragma unroll
    for (int i = 0; i < 8; ++i)
#pragma unroll
        for (int j = 0; j < 8; ++j) acc[i][j] = 0.f;
    for (int d = 0; d < 64; ++d) {
        float a[8], b[8];
#pragma unroll
        for (int wi = 0; wi < 8; ++wi) a[wi] = sqp[ty * 8 + wi][d];
#pragma unroll
        for (int ji = 0; ji < 8; ++ji) b[ji] = skv[ji * 16 + tx][d];
#pragma unroll
        for (int wi = 0; wi < 8; ++wi)
#pragma unroll
            for (int ji = 0; ji < 8; ++ji) acc[wi][ji] += a[wi] * b[ji];
    }
    __syncthreads();   // all q/k LDS reads done; reuse both buffers
    for (int i = 0; i < 16; ++i) {                      // stage V (raw)
        int cid = tid + 128 * i;
        int row = cid >> 4, c4 = (cid & 15) << 2;
        int t = toks[row];
        float4 v4 = *reinterpret_cast<const float4*>(&vg[((size_t)bh * S_ + t) * 64 + c4]);
        skv[row][c4] = v4.x; skv[row][c4 + 1] = v4.y;
        skv[row][c4 + 2] = v4.z; skv[row][c4 + 3] = v4.w;
    }
    float wgt[8];
#pragma unroll
    for (int wi = 0; wi < 8; ++wi) {
        int w = ty * 8 + wi;
        int t = toks[w];
        size_t tb = (size_t)(g & ~3) * S_ + t;
        float l0 = lseg[tb], l1 = lseg[tb + S_], l2 = lseg[tb + 2 * (size_t)S_], l3 = lseg[tb + 3 * (size_t)S_];
        float own = (r == 0) ? l0 : (r == 1) ? l1 : (r == 2) ? l2 : l3;
        float mx = fmaxf(fmaxf(l0, l1), fmaxf(l2, l3));
        float den = expf(l0 - mx) + expf(l1 - mx) + expf(l2 - mx) + expf(l3 - mx);
        wgt[wi] = expf(own - mx) / den;
#pragma unroll
        for (int ji = 0; ji < 8; ++ji)
            sqp[w][ji * 16 + tx] = expf(acc[wi][ji] - own);   // P, full 128 cols
    }
    __syncthreads();
    float o[8][4];
#pragma unroll
    for (int i = 0; i < 8; ++i)
#pragma unroll
        for (int u = 0; u < 4; ++u) o[i][u] = 0.f;
    for (int j = 0; j < 128; ++j) {
        float v0 = skv[j][tx * 4], v1 = skv[j][tx * 4 + 1], v2 = skv[j][tx * 4 + 2], v3 = skv[j][tx * 4 + 3];
#pragma unroll
        for (int wi = 0; wi < 8; ++wi) {
            float p = sqp[ty * 8 + wi][j];
            o[wi][0] += p * v0; o[wi][1] += p * v1; o[wi][2] += p * v2; o[wi][3] += p * v3;
        }
    }
#pragma unroll
    for (int wi = 0; wi < 8; ++wi) {
        int t = toks[ty * 8 + wi];
        float* op = lsh + ((size_t)bh * S_ + t) * 64 + tx * 4;
        float wg = wgt[wi];
#pragma unroll
        for (int u = 0; u < 4; ++u) atomicAdd(&op[u], wg * o[wi][u]);
    }
}

// ---------------------------------------------------------------------------
// Local window attention + gate + mix (wave per token). In-place over lshmix
// (head layout): each thread reads/writes only its own element.
// ---------------------------------------------------------------------------
__global__ __launch_bounds__(256)
void mix_kernel(const float* __restrict__ qk, const float* __restrict__ rnorm,
                const float* __restrict__ vg, float* __restrict__ lshmix,
                const float* __restrict__ w_gate, const float* __restrict__ b_gate,
                float* __restrict__ gpart) {
    __shared__ float gacc[4];
    int tid = threadIdx.x, wv = tid >> 6, lane = tid & 63;
    int row = blockIdx.x * 4 + wv;       // bh*S + s
    int s = row & (S_ - 1);
    int bh = row >> 12;
    int h = bh & 15;
    float qd = qk[(size_t)row * 64 + lane];
    float pw[9], vb[9];
#pragma unroll
    for (int w = 0; w < 9; ++w) {
        int idx = s - 4 + w;
        bool valid = (idx >= 0) && (idx < S_);
        int ic = idx < 0 ? 0 : (idx >= S_ ? S_ - 1 : idx);
        size_t rr = (size_t)bh * S_ + ic;
        float kd = qk[rr * 64 + lane] * rnorm[rr];
        float p = qd * kd;
#pragma unroll
        for (int off = 32; off; off >>= 1) p += __shfl_xor(p, off);
        pw[w] = valid ? p * SCALE_ : -1e9f;
        vb[w] = vg[rr * 64 + lane];
    }
    float mx = pw[0];
#pragma unroll
    for (int w = 1; w < 9; ++w) mx = fmaxf(mx, pw[w]);
    float den = 0.f, loc = 0.f;
#pragma unroll
    for (int w = 0; w < 9; ++w) { float e = expf(pw[w] - mx); den += e; loc += e * vb[w]; }
    loc /= den;
    float gv = qd * w_gate[h * 64 + lane];
#pragma unroll
    for (int off = 32; off; off >>= 1) gv += __shfl_xor(gv, off);
    float gg = sigf(gv + b_gate[h]);
    float lv = lshmix[(size_t)row * 64 + lane];
    lshmix[(size_t)row * 64 + lane] = gg * loc + (1.f - gg) * lv;
    if (lane == 0) gacc[wv] = gg * (1.f - gg);
    __syncthreads();
    if (tid == 0) gpart[blockIdx.x] = gacc[0] + gacc[1] + gacc[2] + gacc[3];
}

__global__ __launch_bounds__(256)
void reg_reduce(const float* __restrict__ gpart, float* __restrict__ outreg) {
    __shared__ float part[4];
    float sm = 0.f;
    for (int i = threadIdx.x; i < 32768; i += 256) sm += gpart[i];
#pragma unroll
    for (int off = 32; off; off >>= 1) sm += __shfl_xor(sm, off);
    if ((threadIdx.x & 63) == 0) part[threadIdx.x >> 6] = sm;
    __syncthreads();
    if (threadIdx.x == 0) outreg[0] = (part[0] + part[1] + part[2] + part[3]) * (1.f / 131072.f);
}

// ---------------------------------------------------------------------------
// LayerNorm over D=1024, block per row
// ---------------------------------------------------------------------------
__global__ __launch_bounds__(256)
void ln_kernel(const float* __restrict__ x, const float* __restrict__ gg,
               const float* __restrict__ bb, float* __restrict__ outp) {
    __shared__ float ps[4][2];
    int row = blockIdx.x, tid = threadIdx.x;
    int wv = tid >> 6, lane = tid & 63;
    const float* xr = x + (size_t)row * 1024;
    float4 xv = *reinterpret_cast<const float4*>(&xr[tid * 4]);
    float s = xv.x + xv.y + xv.z + xv.w;
    float s2 = xv.x * xv.x + xv.y * xv.y + xv.z * xv.z + xv.w * xv.w;
#pragma unroll
    for (int off = 32; off; off >>= 1) { s += __shfl_xor(s, off); s2 += __shfl_xor(s2, off); }
    if (lane == 0) { ps[wv][0] = s; ps[wv][1] = s2; }
    __syncthreads();
    s  = ps[0][0] + ps[1][0] + ps[2][0] + ps[3][0];
    s2 = ps[0][1] + ps[1][1] + ps[2][1] + ps[3][1];
    float mean = s * (1.f / 1024.f);
    float var = s2 * (1.f / 1024.f) - mean * mean;
    float rs = rsqrtf(var + 1e-5f);
    float4 gv = *reinterpret_cast<const float4*>(&gg[tid * 4]);
    float4 bv = *reinterpret_cast<const float4*>(&bb[tid * 4]);
    float4 o;
    o.x = (xv.x - mean) * rs * gv.x + bv.x;
    o.y = (xv.y - mean) * rs * gv.y + bv.y;
    o.z = (xv.z - mean) * rs * gv.z + bv.z;
    o.w = (xv.w - mean) * rs * gv.w + bv.w;
    *reinterpret_cast<float4*>(&outp[(size_t)row * 1024 + tid * 4]) = o;
}

// ---------------------------------------------------------------------------
// Buffer plan (ws usage = 38.4 MB total; round-1 used 70.6 MB -> suspected
// overflow abort):
//   out[0:BSD]      qk  -> y1          (qk dead after mix)
//   out[BSD:2BSD]   v   -> h=LN(y1) -> y2   (v dead after mix; h dead after ffn1)
//   ws bufA 33.5MB  lsh-accum -> mix (in-place, head layout) -> t=relu(h@W1+b1)
//   ws +33.5MB      lseg (2MB)  [aliased: buckets live only before sort]
//   ws +35.6MB      rnorm (0.5MB)
//   ws +36.2MB      perm (2MB)
//   ws +38.2MB      gpart (128KB)
// ---------------------------------------------------------------------------
extern "C" void kernel_launch(void* const* d_in, const int* in_sizes, int n_in,
                              void* d_out, int out_size, void* d_ws, size_t ws_size,
                              hipStream_t stream) {
    (void)in_sizes; (void)n_in; (void)out_size; (void)ws_size;
    const float* x1    = (const float*)d_in[0];
    const float* x2    = (const float*)d_in[1];
    const float* Wqk   = (const float*)d_in[2];
    const float* Wv    = (const float*)d_in[3];
    const float* Wo    = (const float*)d_in[4];
    const float* rot   = (const float*)d_in[5];
    const float* w_gate= (const float*)d_in[6];
    const float* b_gate= (const float*)d_in[7];
    const float* ln_g  = (const float*)d_in[8];
    const float* ln_b  = (const float*)d_in[9];
    const float* W1    = (const float*)d_in[10];
    const float* b1    = (const float*)d_in[11];
    const float* W2    = (const float*)d_in[12];
    const float* b2    = (const float*)d_in[13];
    const float* alpha = (const float*)d_in[14];
    const float* beta  = (const float*)d_in[15];

    float* out = (float*)d_out;
    float* qk  = out;                       // dead after mix_kernel
    float* vv  = out + (size_t)BSD_;        // dead after mix_kernel
    float* y1  = out;
    float* hbuf= out + (size_t)BSD_;        // h = LN(y1), dead after ffn1
    float* y2  = out + (size_t)BSD_;

    char* ws = (char*)d_ws;
    float* bufA   = (float*)(ws + 0);          // lsh accum / mix / t
    float* lseg   = (float*)(ws + 33554432);   // 2 MB (aliases buckets)
    int*   buckets= (int*)  (ws + 33554432);
    float* rnorm  = (float*)(ws + 35651584);   // 0.5 MB
    int*   perm   = (int*)  (ws + 36175872);   // 2 MB
    float* gpart  = (float*)(ws + 38273024);   // 128 KB  (end: 38404096)

    hipMemsetAsync(bufA, 0, (size_t)BSD_ * sizeof(float), stream);

    dim3 gemm_grid(8, 64), gemm_blk(256);
    gemm_f32<0><<<gemm_grid, gemm_blk, 0, stream>>>(x2, Wqk, qk, nullptr, nullptr, nullptr);
    gemm_f32<0><<<gemm_grid, gemm_blk, 0, stream>>>(x2, Wv, vv, nullptr, nullptr, nullptr);
    rnorm_kernel<<<32768, 256, 0, stream>>>(qk, rnorm);
    buckets_kernel<<<dim3(16, 128), 256, 0, stream>>>(qk, rot, buckets);
    sort_kernel<<<128, 256, 0, stream>>>(buckets, perm);
    lse_kernel<<<dim3(64, 128), 128, 0, stream>>>(qk, rnorm, perm, lseg);
    pv_kernel<<<dim3(64, 128), 128, 0, stream>>>(qk, rnorm, vv, perm, lseg, bufA);
    mix_kernel<<<32768, 256, 0, stream>>>(qk, rnorm, vv, bufA, w_gate, b_gate, gpart);
    reg_reduce<<<1, 256, 0, stream>>>(gpart, out + 2 * (size_t)BSD_);
    // y1 = x1 + sigmoid(alpha) * (mix @ Wo)   (mix in head layout -> MODE 1)
    gemm_f32<1><<<gemm_grid, gemm_blk, 0, stream>>>(bufA, Wo, y1, nullptr, x1, alpha);
    // h = LN(y1) -> out[BSD:2BSD]
    ln_kernel<<<8192, 256, 0, stream>>>(y1, ln_g, ln_b, hbuf);
    // t = relu(h @ W1 + b1) -> bufA
    gemm_f32<2><<<gemm_grid, gemm_blk, 0, stream>>>(hbuf, W1, bufA, b1, nullptr, nullptr);
    // y2 = x2 + sigmoid(beta) * (t @ W2 + b2)
    gemm_f32<3><<<gemm_grid, gemm_blk, 0, stream>>>(bufA, W2, y2, b2, x2, beta);
}

// Round 3
// 1814.929 us; speedup vs baseline: 1.3900x; 1.3900x over previous
//
#include <hip/hip_runtime.h>
#include <math.h>

#define B_    2
#define S_    4096
#define D_    1024
#define H_    16
#define DH_   64
#define NH_   4
#define BSD_  8388608     // B*S*D
#define SCALE_ 0.125f     // DH^-0.5

typedef __attribute__((ext_vector_type(8))) short   bf16x8;   // 8 bf16 (4 VGPR)
typedef __attribute__((ext_vector_type(4))) float   f32x4;
typedef __attribute__((ext_vector_type(8))) unsigned short ushort8;
typedef __attribute__((ext_vector_type(4))) unsigned short ushort4v;

__device__ __forceinline__ float sigf(float x) { return 1.f / (1.f + expf(-x)); }

__device__ __forceinline__ unsigned short f2bf(float f) {   // RNE float->bf16 bits
    union { float f; unsigned u; } v; v.f = f;
    unsigned r = v.u + 0x7FFF + ((v.u >> 16) & 1);
    return (unsigned short)(r >> 16);
}

__device__ __forceinline__ void gload_lds16(const void* g, void* l) {
    __builtin_amdgcn_global_load_lds(
        (const __attribute__((address_space(1))) void*)(g),
        (__attribute__((address_space(3))) void*)(l),
        16, 0, 0);
}

// ---------------------------------------------------------------------------
// fp32 GEMM (Wqk only -- bucket path needs fp32): C = A(8192x1024)@W(1024x1024)
// out head-layout [((b*H+h)*S+s)*64+dh]
// ---------------------------------------------------------------------------
__global__ __launch_bounds__(256)
void gemm_f32_qk(const float* __restrict__ A, const float* __restrict__ W,
                 float* __restrict__ out) {
    const int K = 1024, N = 1024;
    __shared__ float As[16][129];
    __shared__ float Bs[16][128];
    const int tid = threadIdx.x;
    const int ty = tid >> 4, tx = tid & 15;
    const int m0 = blockIdx.y * 128, n0 = blockIdx.x * 128;

    float acc[8][8];
#pragma unroll
    for (int i = 0; i < 8; ++i)
#pragma unroll
        for (int j = 0; j < 8; ++j) acc[i][j] = 0.f;

    for (int kt = 0; kt < K; kt += 16) {
#pragma unroll
        for (int l = 0; l < 2; ++l) {
            int cid = tid + l * 256;
            int r  = cid >> 2, c4 = (cid & 3) << 2;
            float4 a4 = *reinterpret_cast<const float4*>(&A[(size_t)(m0 + r) * K + kt + c4]);
            As[c4 + 0][r] = a4.x; As[c4 + 1][r] = a4.y;
            As[c4 + 2][r] = a4.z; As[c4 + 3][r] = a4.w;
            int r2 = cid >> 5, c42 = (cid & 31) << 2;
            *reinterpret_cast<float4*>(&Bs[r2][c42]) =
                *reinterpret_cast<const float4*>(&W[(size_t)(kt + r2) * N + n0 + c42]);
        }
        __syncthreads();
#pragma unroll
        for (int kk = 0; kk < 16; ++kk) {
            float a[8], b[8];
#pragma unroll
            for (int i = 0; i < 8; ++i) a[i] = As[kk][ty * 8 + i];
            float4 b0 = *reinterpret_cast<float4*>(&Bs[kk][tx * 8]);
            float4 b1 = *reinterpret_cast<float4*>(&Bs[kk][tx * 8 + 4]);
            b[0] = b0.x; b[1] = b0.y; b[2] = b0.z; b[3] = b0.w;
            b[4] = b1.x; b[5] = b1.y; b[6] = b1.z; b[7] = b1.w;
#pragma unroll
            for (int i = 0; i < 8; ++i)
#pragma unroll
                for (int j = 0; j < 8; ++j) acc[i][j] += a[i] * b[j];
        }
        __syncthreads();
    }
#pragma unroll
    for (int i = 0; i < 8; ++i) {
        int m = m0 + ty * 8 + i;
        int bb = m >> 12, s = m & 4095;
        int n = n0 + tx * 8;
        int h = n >> 6, dh = n & 63;
        float* op = out + ((((size_t)bb * H_ + h) * S_ + s) << 6) + dh;
        *reinterpret_cast<float4*>(op)     = make_float4(acc[i][0], acc[i][1], acc[i][2], acc[i][3]);
        *reinterpret_cast<float4*>(op + 4) = make_float4(acc[i][4], acc[i][5], acc[i][6], acc[i][7]);
    }
}

// ---------------------------------------------------------------------------
// bf16 MFMA GEMM: C(8192x1024) = A_bf16 @ (BT_bf16)^T, 128x128 tile, BK=32,
// 4 waves each computing a 64x64 quadrant (4x4 fragments of 16x16x32).
// MODE 0: out fp32 head-layout                       (v = x2 @ Wv)
// MODE 1: out fp32 = resid + sigf(gate[n]) * acc     (y1)
// MODE 2: out bf16 = relu(acc + bias[n])             (t)
// MODE 3: out fp32 = resid + sigf(gate[n])*(acc+bias)(y2)
// ---------------------------------------------------------------------------
template<int MODE>
__global__ __launch_bounds__(256)
void gemm_bf16(const unsigned short* __restrict__ A,
               const unsigned short* __restrict__ BT,
               void* __restrict__ outv,
               const float* __restrict__ bias,
               const float* __restrict__ resid,
               const float* __restrict__ gatev) {
    __shared__ __align__(16) unsigned short Als[128 * 32];
    __shared__ __align__(16) unsigned short Bls[128 * 32];
    const int tid = threadIdx.x;
    const int lane = tid & 63, w = tid >> 6;
    const int wr = w >> 1, wc = w & 1;
    const int m0 = blockIdx.y * 128, n0 = blockIdx.x * 128;
    const int l15 = lane & 15, l4 = lane >> 4;

    f32x4 acc[4][4];
#pragma unroll
    for (int i = 0; i < 4; ++i)
#pragma unroll
        for (int j = 0; j < 4; ++j) acc[i][j] = (f32x4)0.f;

    for (int kt = 0; kt < 1024; kt += 32) {
#pragma unroll
        for (int i = 0; i < 2; ++i) {
            int d = i * 256 + tid;               // 16B chunk index 0..511
            int r = d >> 2, sl = d & 3;
            gload_lds16(&A [(size_t)(m0 + r) * 1024 + kt + sl * 8], &Als[(size_t)d * 8]);
            gload_lds16(&BT[(size_t)(n0 + r) * 1024 + kt + sl * 8], &Bls[(size_t)d * 8]);
        }
        __syncthreads();                          // drains vmcnt before reads
        bf16x8 af[4], bf[4];
#pragma unroll
        for (int f = 0; f < 4; ++f) {
            af[f] = *reinterpret_cast<const bf16x8*>(&Als[(size_t)(wr * 64 + f * 16 + l15) * 32 + l4 * 8]);
            bf[f] = *reinterpret_cast<const bf16x8*>(&Bls[(size_t)(wc * 64 + f * 16 + l15) * 32 + l4 * 8]);
        }
#pragma unroll
        for (int fm = 0; fm < 4; ++fm)
#pragma unroll
            for (int fn = 0; fn < 4; ++fn)
                acc[fm][fn] = __builtin_amdgcn_mfma_f32_16x16x32_bf16(af[fm], bf[fn], acc[fm][fn], 0, 0, 0);
        __syncthreads();
    }

#pragma unroll
    for (int fn = 0; fn < 4; ++fn) {
        int n = n0 + wc * 64 + fn * 16 + l15;
        float sg = 0.f, bs = 0.f;
        if (MODE == 1) sg = sigf(gatev[n]);
        if (MODE == 2) bs = bias[n];
        if (MODE == 3) { sg = sigf(gatev[n]); bs = bias[n]; }
#pragma unroll
        for (int fm = 0; fm < 4; ++fm) {
#pragma unroll
            for (int q = 0; q < 4; ++q) {
                int m = m0 + wr * 64 + fm * 16 + l4 * 4 + q;
                float v = acc[fm][fn][q];
                if (MODE == 0) {
                    int bb = m >> 12, s = m & 4095;
                    int h = n >> 6, dh = n & 63;
                    ((float*)outv)[((((size_t)bb * H_ + h) * S_ + s) << 6) + dh] = v;
                } else if (MODE == 1) {
                    size_t idx = (size_t)m * 1024 + n;
                    ((float*)outv)[idx] = resid[idx] + sg * v;
                } else if (MODE == 2) {
                    ((unsigned short*)outv)[(size_t)m * 1024 + n] = f2bf(fmaxf(v + bs, 0.f));
                } else {
                    size_t idx = (size_t)m * 1024 + n;
                    ((float*)outv)[idx] = resid[idx] + sg * (v + bs);
                }
            }
        }
    }
}

// ---------------------------------------------------------------------------
// fp32 -> bf16 elementwise (x2 copy), 8 elems/thread
// ---------------------------------------------------------------------------
__global__ __launch_bounds__(256)
void f2bf_kernel(const float* __restrict__ in, unsigned short* __restrict__ out) {
    size_t i = ((size_t)blockIdx.x * 256 + threadIdx.x) * 8;
    float4 a = *reinterpret_cast<const float4*>(&in[i]);
    float4 b = *reinterpret_cast<const float4*>(&in[i + 4]);
    ushort8 o;
    o[0] = f2bf(a.x); o[1] = f2bf(a.y); o[2] = f2bf(a.z); o[3] = f2bf(a.w);
    o[4] = f2bf(b.x); o[5] = f2bf(b.y); o[6] = f2bf(b.z); o[7] = f2bf(b.w);
    *reinterpret_cast<ushort8*>(&out[i]) = o;
}

// ---------------------------------------------------------------------------
// Weight transpose + convert: W(K=1024,N=1024) f32 -> WT(N,K) bf16
// ---------------------------------------------------------------------------
__global__ __launch_bounds__(256)
void wtrans_kernel(const float* __restrict__ W, unsigned short* __restrict__ WT) {
    __shared__ float tile[32][33];
    int n0 = blockIdx.x * 32, k0 = blockIdx.y * 32;
    int lx = threadIdx.x & 31, ly = threadIdx.x >> 5;
#pragma unroll
    for (int i = 0; i < 4; ++i)
        tile[ly + i * 8][lx] = W[(size_t)(k0 + ly + i * 8) * 1024 + n0 + lx];
    __syncthreads();
#pragma unroll
    for (int i = 0; i < 4; ++i)
        WT[(size_t)(n0 + ly + i * 8) * 1024 + k0 + lx] = f2bf(tile[lx][ly + i * 8]);
}

// ---------------------------------------------------------------------------
// rnorm[row] = 1/(||qk_row|| + 1e-6), wave per row
// ---------------------------------------------------------------------------
__global__ __launch_bounds__(256)
void rnorm_kernel(const float* __restrict__ qk, float* __restrict__ rnorm) {
    int tid = threadIdx.x, wv = tid >> 6, lane = tid & 63;
    int row = blockIdx.x * 4 + wv;
    float q = qk[(size_t)row * 64 + lane];
    float ss = q * q;
#pragma unroll
    for (int off = 32; off; off >>= 1) ss += __shfl_xor(ss, off);
    if (lane == 0) rnorm[row] = 1.f / (sqrtf(ss) + 1e-6f);
}

// ---------------------------------------------------------------------------
// buckets: rotd[m] = sum_d qk[d]*rot[h][r][d][m]; argmax over [rotd,-rotd]
// ---------------------------------------------------------------------------
__global__ __launch_bounds__(256)
void buckets_kernel(const float* __restrict__ qk, const float* __restrict__ rot,
                    int* __restrict__ buckets) {
    int g = blockIdx.y;                  // (b*H+h)*4 + r, 0..127
    int tok = blockIdx.x * 256 + threadIdx.x;
    int r = g & 3;
    int bh = g >> 2;
    int h = bh & 15;
    const float* qrow = qk + ((size_t)bh * S_ + tok) * 64;
    const float* rbase = rot + (size_t)(h * NH_ + r) * 64 * 32;

    float rotd[32];
#pragma unroll
    for (int m = 0; m < 32; ++m) rotd[m] = 0.f;
#pragma unroll
    for (int d4 = 0; d4 < 16; ++d4) {
        float4 q4 = *reinterpret_cast<const float4*>(qrow + (d4 << 2));
        const float* rp = rbase + (d4 << 2) * 32;
#pragma unroll
        for (int m = 0; m < 32; ++m)
            rotd[m] += q4.x * rp[m] + q4.y * rp[32 + m] + q4.z * rp[64 + m] + q4.w * rp[96 + m];
    }
    float bv = rotd[0]; int bi = 0;
#pragma unroll
    for (int m = 1; m < 32; ++m) if (rotd[m] > bv) { bv = rotd[m]; bi = m; }
#pragma unroll
    for (int m = 0; m < 32; ++m) { float nv = -rotd[m]; if (nv > bv) { bv = nv; bi = 32 + m; } }
    buckets[(size_t)g * S_ + tok] = bi;
}

// ---------------------------------------------------------------------------
// Stable counting sort per group g: perm = argsort(bucket*S + pos)
// ---------------------------------------------------------------------------
__global__ __launch_bounds__(256)
void sort_kernel(const int* __restrict__ buckets, int* __restrict__ perm) {
    __shared__ int bk[4096];
    __shared__ int qcnt[4][64];
    __shared__ int qoff[4][64];
    __shared__ int ps[4096];
    int g = blockIdx.x, tid = threadIdx.x;
    const int* bp = buckets + (size_t)g * S_;
    for (int i = 0; i < 16; ++i) bk[tid + 256 * i] = bp[tid + 256 * i];
    qcnt[tid >> 6][tid & 63] = 0;
    __syncthreads();
    int q = tid >> 6, l = tid & 63;
    for (int i = 0; i < 16; ++i) {
        int pos = q * 1024 + l + 64 * i;
        atomicAdd(&qcnt[q][bk[pos]], 1);
    }
    __syncthreads();
    if (tid == 0) {
        int run = 0;
        for (int b = 0; b < 64; ++b)
            for (int qq = 0; qq < 4; ++qq) { qoff[qq][b] = run; run += qcnt[qq][b]; }
    }
    __syncthreads();
    {
        int base = qoff[q][l], cnt = 0;
        for (int j = q * 1024; j < q * 1024 + 1024; ++j) {
            if (bk[j] == l) { ps[base + cnt] = j; ++cnt; }
        }
    }
    __syncthreads();
    int* pp = perm + (size_t)g * S_;
    for (int i = 0; i < 16; ++i) pp[tid + 256 * i] = ps[tid + 256 * i];
}

// ---------------------------------------------------------------------------
// Attention pass 1: per (g, chunk) compute dots(64x128), write per-token lse.
// ---------------------------------------------------------------------------
__global__ __launch_bounds__(128)
void lse_kernel(const float* __restrict__ qk, const float* __restrict__ rnorm,
                const int* __restrict__ perm, float* __restrict__ lseg) {
    __shared__ float sq[64][65];
    __shared__ float sk[128][65];
    __shared__ int toks[128];
    int g = blockIdx.y, c = blockIdx.x, tid = threadIdx.x;
    int bh = g >> 2;
    int pc = (c + 63) & 63;
    toks[tid] = (tid < 64) ? perm[(size_t)g * S_ + c * 64 + tid]
                           : perm[(size_t)g * S_ + pc * 64 + (tid - 64)];
    __syncthreads();
    for (int i = 0; i < 8; ++i) {
        int cid = tid + 128 * i;
        int row = cid >> 4, c4 = (cid & 15) << 2;
        int t = toks[row];
        float4 v4 = *reinterpret_cast<const float4*>(&qk[((size_t)bh * S_ + t) * 64 + c4]);
        sq[row][c4] = v4.x * SCALE_; sq[row][c4 + 1] = v4.y * SCALE_;
        sq[row][c4 + 2] = v4.z * SCALE_; sq[row][c4 + 3] = v4.w * SCALE_;
    }
    for (int i = 0; i < 16; ++i) {
        int cid = tid + 128 * i;
        int row = cid >> 4, c4 = (cid & 15) << 2;
        int t = toks[row];
        float rn = rnorm[(size_t)bh * S_ + t];
        float4 v4 = *reinterpret_cast<const float4*>(&qk[((size_t)bh * S_ + t) * 64 + c4]);
        sk[row][c4] = v4.x * rn; sk[row][c4 + 1] = v4.y * rn;
        sk[row][c4 + 2] = v4.z * rn; sk[row][c4 + 3] = v4.w * rn;
    }
    __syncthreads();
    int ty = tid >> 4, tx = tid & 15;
    float acc[8][8];
#pragma unroll
    for (int i = 0; i < 8; ++i)
#pragma unroll
        for (int j = 0; j < 8; ++j) acc[i][j] = 0.f;
    for (int d = 0; d < 64; ++d) {
        float a[8], b[8];
#pragma unroll
        for (int wi = 0; wi < 8; ++wi) a[wi] = sq[ty * 8 + wi][d];
#pragma unroll
        for (int ji = 0; ji < 8; ++ji) b[ji] = sk[ji * 16 + tx][d];
#pragma unroll
        for (int wi = 0; wi < 8; ++wi)
#pragma unroll
            for (int ji = 0; ji < 8; ++ji) acc[wi][ji] += a[wi] * b[ji];
    }
#pragma unroll
    for (int wi = 0; wi < 8; ++wi) {
        float mx = acc[wi][0];
#pragma unroll
        for (int ji = 1; ji < 8; ++ji) mx = fmaxf(mx, acc[wi][ji]);
#pragma unroll
        for (int off = 8; off; off >>= 1) mx = fmaxf(mx, __shfl_xor(mx, off));
        float sm = 0.f;
#pragma unroll
        for (int ji = 0; ji < 8; ++ji) sm += expf(acc[wi][ji] - mx);
#pragma unroll
        for (int off = 8; off; off >>= 1) sm += __shfl_xor(sm, off);
        if (tx == 0) lseg[(size_t)g * S_ + toks[ty * 8 + wi]] = mx + logf(sm);
    }
}

// ---------------------------------------------------------------------------
// Attention pass 2: recompute dots, p = exp(dots - lse_total-normalized),
// o = p@V, atomically accumulate round-weighted o into lsh.
// ---------------------------------------------------------------------------
__global__ __launch_bounds__(128)
void pv_kernel(const float* __restrict__ qk, const float* __restrict__ rnorm,
               const float* __restrict__ vg, const int* __restrict__ perm,
               const float* __restrict__ lseg, float* __restrict__ lsh) {
    __shared__ float sqp[64][130];   // q staging (cols 0..63), then P (128 cols)
    __shared__ float skv[128][65];   // K staging, then V
    __shared__ int toks[128];
    int g = blockIdx.y, c = blockIdx.x, tid = threadIdx.x;
    int bh = g >> 2, r = g & 3;
    int pc = (c + 63) & 63;
    toks[tid] = (tid < 64) ? perm[(size_t)g * S_ + c * 64 + tid]
                           : perm[(size_t)g * S_ + pc * 64 + (tid - 64)];
    __syncthreads();
    for (int i = 0; i < 8; ++i) {
        int cid = tid + 128 * i;
        int row = cid >> 4, c4 = (cid & 15) << 2;
        int t = toks[row];
        float4 v4 = *reinterpret_cast<const float4*>(&qk[((size_t)bh * S_ + t) * 64 + c4]);
        sqp[row][c4] = v4.x * SCALE_; sqp[row][c4 + 1] = v4.y * SCALE_;
        sqp[row][c4 + 2] = v4.z * SCALE_; sqp[row][c4 + 3] = v4.w * SCALE_;
    }
    for (int i = 0; i < 16; ++i) {
        int cid = tid + 128 * i;
        int row = cid >> 4, c4 = (cid & 15) << 2;
        int t = toks[row];
        float rn = rnorm[(size_t)bh * S_ + t];
        float4 v4 = *reinterpret_cast<const float4*>(&qk[((size_t)bh * S_ + t) * 64 + c4]);
        skv[row][c4] = v4.x * rn; skv[row][c4 + 1] = v4.y * rn;
        skv[row][c4 + 2] = v4.z * rn; skv[row][c4 + 3] = v4.w * rn;
    }
    __syncthreads();
    int ty = tid >> 4, tx = tid & 15;
    float acc[8][8];
#pragma unroll
    for (int i = 0; i < 8; ++i)
#pragma unroll
        for (int j = 0; j < 8; ++j) acc[i][j] = 0.f;
    for (int d = 0; d < 64; ++d) {
        float a[8], b[8];
#pragma unroll
        for (int wi = 0; wi < 8; ++wi) a[wi] = sqp[ty * 8 + wi][d];
#pragma unroll
        for (int ji = 0; ji < 8; ++ji) b[ji] = skv[ji * 16 + tx][d];
#pragma unroll
        for (int wi = 0; wi < 8; ++wi)
#pragma unroll
            for (int ji = 0; ji < 8; ++ji) acc[wi][ji] += a[wi] * b[ji];
    }
    __syncthreads();
    for (int i = 0; i < 16; ++i) {                      // stage V (raw)
        int cid = tid + 128 * i;
        int row = cid >> 4, c4 = (cid & 15) << 2;
        int t = toks[row];
        float4 v4 = *reinterpret_cast<const float4*>(&vg[((size_t)bh * S_ + t) * 64 + c4]);
        skv[row][c4] = v4.x; skv[row][c4 + 1] = v4.y;
        skv[row][c4 + 2] = v4.z; skv[row][c4 + 3] = v4.w;
    }
    float wgt[8];
#pragma unroll
    for (int wi = 0; wi < 8; ++wi) {
        int w = ty * 8 + wi;
        int t = toks[w];
        size_t tb = (size_t)(g & ~3) * S_ + t;
        float l0 = lseg[tb], l1 = lseg[tb + S_], l2 = lseg[tb + 2 * (size_t)S_], l3 = lseg[tb + 3 * (size_t)S_];
        float own = (r == 0) ? l0 : (r == 1) ? l1 : (r == 2) ? l2 : l3;
        float mx = fmaxf(fmaxf(l0, l1), fmaxf(l2, l3));
        float den = expf(l0 - mx) + expf(l1 - mx) + expf(l2 - mx) + expf(l3 - mx);
        wgt[wi] = expf(own - mx) / den;
#pragma unroll
        for (int ji = 0; ji < 8; ++ji)
            sqp[w][ji * 16 + tx] = expf(acc[wi][ji] - own);
    }
    __syncthreads();
    float o[8][4];
#pragma unroll
    for (int i = 0; i < 8; ++i)
#pragma unroll
        for (int u = 0; u < 4; ++u) o[i][u] = 0.f;
    for (int j = 0; j < 128; ++j) {
        float v0 = skv[j][tx * 4], v1 = skv[j][tx * 4 + 1], v2 = skv[j][tx * 4 + 2], v3 = skv[j][tx * 4 + 3];
#pragma unroll
        for (int wi = 0; wi < 8; ++wi) {
            float p = sqp[ty * 8 + wi][j];
            o[wi][0] += p * v0; o[wi][1] += p * v1; o[wi][2] += p * v2; o[wi][3] += p * v3;
        }
    }
#pragma unroll
    for (int wi = 0; wi < 8; ++wi) {
        int t = toks[ty * 8 + wi];
        float* op = lsh + ((size_t)bh * S_ + t) * 64 + tx * 4;
        float wg = wgt[wi];
#pragma unroll
        for (int u = 0; u < 4; ++u) atomicAdd(&op[u], wg * o[wi][u]);
    }
}

// ---------------------------------------------------------------------------
// Local window attention + gate + mix. Reads lsh (head layout fp32), writes
// mixb bf16 in flat (B,S,D) layout (feeds Wo MFMA GEMM).
// ---------------------------------------------------------------------------
__global__ __launch_bounds__(256)
void mix_kernel(const float* __restrict__ qk, const float* __restrict__ rnorm,
                const float* __restrict__ vg, const float* __restrict__ lsh,
                const float* __restrict__ w_gate, const float* __restrict__ b_gate,
                unsigned short* __restrict__ mixb, float* __restrict__ gpart) {
    __shared__ float gacc[4];
    int tid = threadIdx.x, wv = tid >> 6, lane = tid & 63;
    int row = blockIdx.x * 4 + wv;       // bh*S + s
    int s = row & (S_ - 1);
    int bh = row >> 12;
    int h = bh & 15, b = bh >> 4;
    float qd = qk[(size_t)row * 64 + lane];
    float pw[9], vb[9];
#pragma unroll
    for (int w = 0; w < 9; ++w) {
        int idx = s - 4 + w;
        bool valid = (idx >= 0) && (idx < S_);
        int ic = idx < 0 ? 0 : (idx >= S_ ? S_ - 1 : idx);
        size_t rr = (size_t)bh * S_ + ic;
        float kd = qk[rr * 64 + lane] * rnorm[rr];
        float p = qd * kd;
#pragma unroll
        for (int off = 32; off; off >>= 1) p += __shfl_xor(p, off);
        pw[w] = valid ? p * SCALE_ : -1e9f;
        vb[w] = vg[rr * 64 + lane];
    }
    float mx = pw[0];
#pragma unroll
    for (int w = 1; w < 9; ++w) mx = fmaxf(mx, pw[w]);
    float den = 0.f, loc = 0.f;
#pragma unroll
    for (int w = 0; w < 9; ++w) { float e = expf(pw[w] - mx); den += e; loc += e * vb[w]; }
    loc /= den;
    float gv = qd * w_gate[h * 64 + lane];
#pragma unroll
    for (int off = 32; off; off >>= 1) gv += __shfl_xor(gv, off);
    float gg = sigf(gv + b_gate[h]);
    float lv = lsh[(size_t)row * 64 + lane];
    float mval = gg * loc + (1.f - gg) * lv;
    mixb[((size_t)b * S_ + s) * 1024 + h * 64 + lane] = f2bf(mval);
    if (lane == 0) gacc[wv] = gg * (1.f - gg);
    __syncthreads();
    if (tid == 0) gpart[blockIdx.x] = gacc[0] + gacc[1] + gacc[2] + gacc[3];
}

__global__ __launch_bounds__(256)
void reg_reduce(const float* __restrict__ gpart, float* __restrict__ outreg) {
    __shared__ float part[4];
    float sm = 0.f;
    for (int i = threadIdx.x; i < 32768; i += 256) sm += gpart[i];
#pragma unroll
    for (int off = 32; off; off >>= 1) sm += __shfl_xor(sm, off);
    if ((threadIdx.x & 63) == 0) part[threadIdx.x >> 6] = sm;
    __syncthreads();
    if (threadIdx.x == 0) outreg[0] = (part[0] + part[1] + part[2] + part[3]) * (1.f / 131072.f);
}

// ---------------------------------------------------------------------------
// LayerNorm over D=1024, block per row; writes bf16 h (feeds W1 MFMA GEMM)
// ---------------------------------------------------------------------------
__global__ __launch_bounds__(256)
void ln_kernel(const float* __restrict__ x, const float* __restrict__ gg,
               const float* __restrict__ bb, unsigned short* __restrict__ outp) {
    __shared__ float ps[4][2];
    int row = blockIdx.x, tid = threadIdx.x;
    int wv = tid >> 6, lane = tid & 63;
    const float* xr = x + (size_t)row * 1024;
    float4 xv = *reinterpret_cast<const float4*>(&xr[tid * 4]);
    float s = xv.x + xv.y + xv.z + xv.w;
    float s2 = xv.x * xv.x + xv.y * xv.y + xv.z * xv.z + xv.w * xv.w;
#pragma unroll
    for (int off = 32; off; off >>= 1) { s += __shfl_xor(s, off); s2 += __shfl_xor(s2, off); }
    if (lane == 0) { ps[wv][0] = s; ps[wv][1] = s2; }
    __syncthreads();
    s  = ps[0][0] + ps[1][0] + ps[2][0] + ps[3][0];
    s2 = ps[0][1] + ps[1][1] + ps[2][1] + ps[3][1];
    float mean = s * (1.f / 1024.f);
    float var = s2 * (1.f / 1024.f) - mean * mean;
    float rs = rsqrtf(var + 1e-5f);
    float4 gv = *reinterpret_cast<const float4*>(&gg[tid * 4]);
    float4 bv = *reinterpret_cast<const float4*>(&bb[tid * 4]);
    ushort4v o;
    o[0] = f2bf((xv.x - mean) * rs * gv.x + bv.x);
    o[1] = f2bf((xv.y - mean) * rs * gv.y + bv.y);
    o[2] = f2bf((xv.z - mean) * rs * gv.z + bv.z);
    o[3] = f2bf((xv.w - mean) * rs * gv.w + bv.w);
    *reinterpret_cast<ushort4v*>(&outp[(size_t)row * 1024 + tid * 4]) = o;
}

// ---------------------------------------------------------------------------
// ws layout (63.6 MB):
//   0:          bufA fp32 lsh-accum (33.5MB); after mix dead ->
//               h_bf16 @0 (16.8MB), t_bf16 @16777216 (16.8MB)
//   33554432:   x2b bf16 (16.8MB); dead after Wv GEMM -> mixb bf16 (same slot)
//   50331648:   WvT/WoT/W1T/W2T bf16, 2MB each (8.4MB)
//   58720256:   lseg fp32 2MB (aliases buckets int 2MB, disjoint lifetime)
//   60817408:   perm int 2MB
//   62914560:   rnorm fp32 0.5MB
//   63438848:   gpart fp32 128KB
// d_out: qk -> y1 @0; v -> y2 @BSD; reg @2*BSD
// ---------------------------------------------------------------------------
extern "C" void kernel_launch(void* const* d_in, const int* in_sizes, int n_in,
                              void* d_out, int out_size, void* d_ws, size_t ws_size,
                              hipStream_t stream) {
    (void)in_sizes; (void)n_in; (void)out_size; (void)ws_size;
    const float* x1    = (const float*)d_in[0];
    const float* x2    = (const float*)d_in[1];
    const float* Wqk   = (const float*)d_in[2];
    const float* Wv    = (const float*)d_in[3];
    const float* Wo    = (const float*)d_in[4];
    const float* rot   = (const float*)d_in[5];
    const float* w_gate= (const float*)d_in[6];
    const float* b_gate= (const float*)d_in[7];
    const float* ln_g  = (const float*)d_in[8];
    const float* ln_b  = (const float*)d_in[9];
    const float* W1    = (const float*)d_in[10];
    const float* b1    = (const float*)d_in[11];
    const float* W2    = (const float*)d_in[12];
    const float* b2    = (const float*)d_in[13];
    const float* alpha = (const float*)d_in[14];
    const float* beta  = (const float*)d_in[15];

    float* out = (float*)d_out;
    float* qk  = out;
    float* vv  = out + (size_t)BSD_;
    float* y1  = out;
    float* y2  = out + (size_t)BSD_;

    char* ws = (char*)d_ws;
    float* bufA           = (float*)(ws + 0);
    unsigned short* hb    = (unsigned short*)(ws + 0);
    unsigned short* tb    = (unsigned short*)(ws + 16777216);
    unsigned short* x2b   = (unsigned short*)(ws + 33554432);
    unsigned short* mixb  = (unsigned short*)(ws + 33554432);
    unsigned short* WvT   = (unsigned short*)(ws + 50331648);
    unsigned short* WoT   = (unsigned short*)(ws + 52428800);
    unsigned short* W1T   = (unsigned short*)(ws + 54525952);
    unsigned short* W2T   = (unsigned short*)(ws + 56623104);
    float* lseg           = (float*)(ws + 58720256);
    int*   buckets        = (int*)  (ws + 58720256);
    int*   perm           = (int*)  (ws + 60817408);
    float* rnorm          = (float*)(ws + 62914560);
    float* gpart          = (float*)(ws + 63438848);

    hipMemsetAsync(bufA, 0, (size_t)BSD_ * sizeof(float), stream);

    dim3 gg(8, 64), gb(256);
    dim3 tg(32, 32);
    f2bf_kernel<<<4096, 256, 0, stream>>>(x2, x2b);
    wtrans_kernel<<<tg, 256, 0, stream>>>(Wv, WvT);
    wtrans_kernel<<<tg, 256, 0, stream>>>(Wo, WoT);
    wtrans_kernel<<<tg, 256, 0, stream>>>(W1, W1T);
    wtrans_kernel<<<tg, 256, 0, stream>>>(W2, W2T);

    gemm_f32_qk<<<gg, gb, 0, stream>>>(x2, Wqk, qk);               // fp32 (buckets!)
    gemm_bf16<0><<<gg, gb, 0, stream>>>(x2b, WvT, vv, nullptr, nullptr, nullptr);

    rnorm_kernel<<<32768, 256, 0, stream>>>(qk, rnorm);
    buckets_kernel<<<dim3(16, 128), 256, 0, stream>>>(qk, rot, buckets);
    sort_kernel<<<128, 256, 0, stream>>>(buckets, perm);
    lse_kernel<<<dim3(64, 128), 128, 0, stream>>>(qk, rnorm, perm, lseg);
    pv_kernel<<<dim3(64, 128), 128, 0, stream>>>(qk, rnorm, vv, perm, lseg, bufA);
    mix_kernel<<<32768, 256, 0, stream>>>(qk, rnorm, vv, bufA, w_gate, b_gate, mixb, gpart);
    reg_reduce<<<1, 256, 0, stream>>>(gpart, out + 2 * (size_t)BSD_);

    // y1 = x1 + sigmoid(alpha) * (mix @ Wo)
    gemm_bf16<1><<<gg, gb, 0, stream>>>(mixb, WoT, y1, nullptr, x1, alpha);
    // h = LN(y1) -> bf16
    ln_kernel<<<8192, 256, 0, stream>>>(y1, ln_g, ln_b, hb);
    // t = relu(h @ W1 + b1) -> bf16
    gemm_bf16<2><<<gg, gb, 0, stream>>>(hb, W1T, tb, b1, nullptr, nullptr);
    // y2 = x2 + sigmoid(beta) * (t @ W2 + b2)
    gemm_bf16<3><<<gg, gb, 0, stream>>>(tb, W2T, y2, b2, x2, beta);
}

// Round 4
// 1043.093 us; speedup vs baseline: 2.4185x; 1.7399x over previous
//
#include <hip/hip_runtime.h>
#include <math.h>

#define B_    2
#define S_    4096
#define D_    1024
#define H_    16
#define DH_   64
#define NH_   4
#define BSD_  8388608     // B*S*D
#define SCALE_ 0.125f     // DH^-0.5

typedef __attribute__((ext_vector_type(8))) short   bf16x8;   // 8 bf16 (4 VGPR)
typedef __attribute__((ext_vector_type(4))) float   f32x4;
typedef __attribute__((ext_vector_type(8))) unsigned short ushort8;
typedef __attribute__((ext_vector_type(4))) unsigned short ushort4v;

__device__ __forceinline__ float sigf(float x) { return 1.f / (1.f + expf(-x)); }

__device__ __forceinline__ unsigned short f2bf(float f) {   // RNE float->bf16 bits
    union { float f; unsigned u; } v; v.f = f;
    unsigned r = v.u + 0x7FFF + ((v.u >> 16) & 1);
    return (unsigned short)(r >> 16);
}
__device__ __forceinline__ float bf2f(unsigned short u) {
    union { unsigned u; float f; } v; v.u = ((unsigned)u) << 16; return v.f;
}

__device__ __forceinline__ void gload_lds16(const void* g, void* l) {
    __builtin_amdgcn_global_load_lds(
        (const __attribute__((address_space(1))) void*)(g),
        (__attribute__((address_space(3))) void*)(l),
        16, 0, 0);
}

// ---------------------------------------------------------------------------
// fp32 GEMM (Wqk only -- bucket argmax needs fp32): C = A @ W,
// out head-layout [((b*H+h)*S+s)*64+dh]
// ---------------------------------------------------------------------------
__global__ __launch_bounds__(256)
void gemm_f32_qk(const float* __restrict__ A, const float* __restrict__ W,
                 float* __restrict__ out) {
    const int K = 1024, N = 1024;
    __shared__ float As[16][129];
    __shared__ float Bs[16][128];
    const int tid = threadIdx.x;
    const int ty = tid >> 4, tx = tid & 15;
    const int m0 = blockIdx.y * 128, n0 = blockIdx.x * 128;

    float acc[8][8];
#pragma unroll
    for (int i = 0; i < 8; ++i)
#pragma unroll
        for (int j = 0; j < 8; ++j) acc[i][j] = 0.f;

    for (int kt = 0; kt < K; kt += 16) {
#pragma unroll
        for (int l = 0; l < 2; ++l) {
            int cid = tid + l * 256;
            int r  = cid >> 2, c4 = (cid & 3) << 2;
            float4 a4 = *reinterpret_cast<const float4*>(&A[(size_t)(m0 + r) * K + kt + c4]);
            As[c4 + 0][r] = a4.x; As[c4 + 1][r] = a4.y;
            As[c4 + 2][r] = a4.z; As[c4 + 3][r] = a4.w;
            int r2 = cid >> 5, c42 = (cid & 31) << 2;
            *reinterpret_cast<float4*>(&Bs[r2][c42]) =
                *reinterpret_cast<const float4*>(&W[(size_t)(kt + r2) * N + n0 + c42]);
        }
        __syncthreads();
#pragma unroll
        for (int kk = 0; kk < 16; ++kk) {
            float a[8], b[8];
#pragma unroll
            for (int i = 0; i < 8; ++i) a[i] = As[kk][ty * 8 + i];
            float4 b0 = *reinterpret_cast<float4*>(&Bs[kk][tx * 8]);
            float4 b1 = *reinterpret_cast<float4*>(&Bs[kk][tx * 8 + 4]);
            b[0] = b0.x; b[1] = b0.y; b[2] = b0.z; b[3] = b0.w;
            b[4] = b1.x; b[5] = b1.y; b[6] = b1.z; b[7] = b1.w;
#pragma unroll
            for (int i = 0; i < 8; ++i)
#pragma unroll
                for (int j = 0; j < 8; ++j) acc[i][j] += a[i] * b[j];
        }
        __syncthreads();
    }
#pragma unroll
    for (int i = 0; i < 8; ++i) {
        int m = m0 + ty * 8 + i;
        int bb = m >> 12, s = m & 4095;
        int n = n0 + tx * 8;
        int h = n >> 6, dh = n & 63;
        float* op = out + ((((size_t)bb * H_ + h) * S_ + s) << 6) + dh;
        *reinterpret_cast<float4*>(op)     = make_float4(acc[i][0], acc[i][1], acc[i][2], acc[i][3]);
        *reinterpret_cast<float4*>(op + 4) = make_float4(acc[i][4], acc[i][5], acc[i][6], acc[i][7]);
    }
}

// ---------------------------------------------------------------------------
// bf16 MFMA GEMM, 128x128 tile, BK=32, 4 waves x (64x64 quadrant).
// MODE 0: out bf16 head-layout                       (v = x2 @ Wv)
// MODE 1: out fp32 = resid + sigf(gate[n]) * acc     (y1)
// MODE 2: out bf16 = relu(acc + bias[n])             (t)
// MODE 3: out fp32 = resid + sigf(gate[n])*(acc+bias)(y2)
// ---------------------------------------------------------------------------
template<int MODE>
__global__ __launch_bounds__(256)
void gemm_bf16(const unsigned short* __restrict__ A,
               const unsigned short* __restrict__ BT,
               void* __restrict__ outv,
               const float* __restrict__ bias,
               const float* __restrict__ resid,
               const float* __restrict__ gatev) {
    __shared__ __align__(16) unsigned short Als[128 * 32];
    __shared__ __align__(16) unsigned short Bls[128 * 32];
    const int tid = threadIdx.x;
    const int lane = tid & 63, w = tid >> 6;
    const int wr = w >> 1, wc = w & 1;
    const int m0 = blockIdx.y * 128, n0 = blockIdx.x * 128;
    const int l15 = lane & 15, l4 = lane >> 4;

    f32x4 acc[4][4];
#pragma unroll
    for (int i = 0; i < 4; ++i)
#pragma unroll
        for (int j = 0; j < 4; ++j) acc[i][j] = (f32x4)0.f;

    for (int kt = 0; kt < 1024; kt += 32) {
#pragma unroll
        for (int i = 0; i < 2; ++i) {
            int d = i * 256 + tid;
            int r = d >> 2, sl = d & 3;
            gload_lds16(&A [(size_t)(m0 + r) * 1024 + kt + sl * 8], &Als[(size_t)d * 8]);
            gload_lds16(&BT[(size_t)(n0 + r) * 1024 + kt + sl * 8], &Bls[(size_t)d * 8]);
        }
        __syncthreads();
        bf16x8 af[4], bfr[4];
#pragma unroll
        for (int f = 0; f < 4; ++f) {
            af[f]  = *reinterpret_cast<const bf16x8*>(&Als[(size_t)(wr * 64 + f * 16 + l15) * 32 + l4 * 8]);
            bfr[f] = *reinterpret_cast<const bf16x8*>(&Bls[(size_t)(wc * 64 + f * 16 + l15) * 32 + l4 * 8]);
        }
#pragma unroll
        for (int fm = 0; fm < 4; ++fm)
#pragma unroll
            for (int fn = 0; fn < 4; ++fn)
                acc[fm][fn] = __builtin_amdgcn_mfma_f32_16x16x32_bf16(af[fm], bfr[fn], acc[fm][fn], 0, 0, 0);
        __syncthreads();
    }

#pragma unroll
    for (int fn = 0; fn < 4; ++fn) {
        int n = n0 + wc * 64 + fn * 16 + l15;
        float sg = 0.f, bs = 0.f;
        if (MODE == 1) sg = sigf(gatev[n]);
        if (MODE == 2) bs = bias[n];
        if (MODE == 3) { sg = sigf(gatev[n]); bs = bias[n]; }
#pragma unroll
        for (int fm = 0; fm < 4; ++fm) {
#pragma unroll
            for (int q = 0; q < 4; ++q) {
                int m = m0 + wr * 64 + fm * 16 + l4 * 4 + q;
                float v = acc[fm][fn][q];
                if (MODE == 0) {
                    int bb = m >> 12, s = m & 4095;
                    int h = n >> 6, dh = n & 63;
                    ((unsigned short*)outv)[((((size_t)bb * H_ + h) * S_ + s) << 6) + dh] = f2bf(v);
                } else if (MODE == 1) {
                    size_t idx = (size_t)m * 1024 + n;
                    ((float*)outv)[idx] = resid[idx] + sg * v;
                } else if (MODE == 2) {
                    ((unsigned short*)outv)[(size_t)m * 1024 + n] = f2bf(fmaxf(v + bs, 0.f));
                } else {
                    size_t idx = (size_t)m * 1024 + n;
                    ((float*)outv)[idx] = resid[idx] + sg * (v + bs);
                }
            }
        }
    }
}

// ---------------------------------------------------------------------------
// fp32 -> bf16 elementwise (x2 copy)
// ---------------------------------------------------------------------------
__global__ __launch_bounds__(256)
void f2bf_kernel(const float* __restrict__ in, unsigned short* __restrict__ out) {
    size_t i = ((size_t)blockIdx.x * 256 + threadIdx.x) * 8;
    float4 a = *reinterpret_cast<const float4*>(&in[i]);
    float4 b = *reinterpret_cast<const float4*>(&in[i + 4]);
    ushort8 o;
    o[0] = f2bf(a.x); o[1] = f2bf(a.y); o[2] = f2bf(a.z); o[3] = f2bf(a.w);
    o[4] = f2bf(b.x); o[5] = f2bf(b.y); o[6] = f2bf(b.z); o[7] = f2bf(b.w);
    *reinterpret_cast<ushort8*>(&out[i]) = o;
}

// ---------------------------------------------------------------------------
// Weight transpose + convert: W(K,N) f32 -> WT(N,K) bf16
// ---------------------------------------------------------------------------
__global__ __launch_bounds__(256)
void wtrans_kernel(const float* __restrict__ W, unsigned short* __restrict__ WT) {
    __shared__ float tile[32][33];
    int n0 = blockIdx.x * 32, k0 = blockIdx.y * 32;
    int lx = threadIdx.x & 31, ly = threadIdx.x >> 5;
#pragma unroll
    for (int i = 0; i < 4; ++i)
        tile[ly + i * 8][lx] = W[(size_t)(k0 + ly + i * 8) * 1024 + n0 + lx];
    __syncthreads();
#pragma unroll
    for (int i = 0; i < 4; ++i)
        WT[(size_t)(n0 + ly + i * 8) * 1024 + k0 + lx] = f2bf(tile[lx][ly + i * 8]);
}

// ---------------------------------------------------------------------------
// stage: per row, qnorm[row] = |q|, qb = bf16(q) (head layout). Wave per row.
// ---------------------------------------------------------------------------
__global__ __launch_bounds__(256)
void stage_kernel(const float* __restrict__ qk, unsigned short* __restrict__ qb,
                  float* __restrict__ qnorm) {
    int tid = threadIdx.x, wv = tid >> 6, lane = tid & 63;
    int row = blockIdx.x * 4 + wv;
    float q = qk[(size_t)row * 64 + lane];
    float ss = q * q;
#pragma unroll
    for (int off = 32; off; off >>= 1) ss += __shfl_xor(ss, off);
    if (lane == 0) qnorm[row] = sqrtf(ss);
    qb[(size_t)row * 64 + lane] = f2bf(q);
}

// ---------------------------------------------------------------------------
// buckets (fp32 qk): rotd argmax over [rotd,-rotd]
// ---------------------------------------------------------------------------
__global__ __launch_bounds__(256)
void buckets_kernel(const float* __restrict__ qk, const float* __restrict__ rot,
                    int* __restrict__ buckets) {
    int g = blockIdx.y;
    int tok = blockIdx.x * 256 + threadIdx.x;
    int r = g & 3;
    int bh = g >> 2;
    int h = bh & 15;
    const float* qrow = qk + ((size_t)bh * S_ + tok) * 64;
    const float* rbase = rot + (size_t)(h * NH_ + r) * 64 * 32;

    float rotd[32];
#pragma unroll
    for (int m = 0; m < 32; ++m) rotd[m] = 0.f;
#pragma unroll
    for (int d4 = 0; d4 < 16; ++d4) {
        float4 q4 = *reinterpret_cast<const float4*>(qrow + (d4 << 2));
        const float* rp = rbase + (d4 << 2) * 32;
#pragma unroll
        for (int m = 0; m < 32; ++m)
            rotd[m] += q4.x * rp[m] + q4.y * rp[32 + m] + q4.z * rp[64 + m] + q4.w * rp[96 + m];
    }
    float bv = rotd[0]; int bi = 0;
#pragma unroll
    for (int m = 1; m < 32; ++m) if (rotd[m] > bv) { bv = rotd[m]; bi = m; }
#pragma unroll
    for (int m = 0; m < 32; ++m) { float nv = -rotd[m]; if (nv > bv) { bv = nv; bi = 32 + m; } }
    buckets[(size_t)g * S_ + tok] = bi;
}

// ---------------------------------------------------------------------------
// Stable counting sort per group g: perm = argsort(bucket*S + pos)
// ---------------------------------------------------------------------------
__global__ __launch_bounds__(256)
void sort_kernel(const int* __restrict__ buckets, int* __restrict__ perm) {
    __shared__ int bk[4096];
    __shared__ int qcnt[4][64];
    __shared__ int qoff[4][64];
    __shared__ int ps[4096];
    int g = blockIdx.x, tid = threadIdx.x;
    const int* bp = buckets + (size_t)g * S_;
    for (int i = 0; i < 16; ++i) bk[tid + 256 * i] = bp[tid + 256 * i];
    qcnt[tid >> 6][tid & 63] = 0;
    __syncthreads();
    int q = tid >> 6, l = tid & 63;
    for (int i = 0; i < 16; ++i) {
        int pos = q * 1024 + l + 64 * i;
        atomicAdd(&qcnt[q][bk[pos]], 1);
    }
    __syncthreads();
    if (tid == 0) {
        int run = 0;
        for (int b = 0; b < 64; ++b)
            for (int qq = 0; qq < 4; ++qq) { qoff[qq][b] = run; run += qcnt[qq][b]; }
    }
    __syncthreads();
    {
        int base = qoff[q][l], cnt = 0;
        for (int j = q * 1024; j < q * 1024 + 1024; ++j) {
            if (bk[j] == l) { ps[base + cnt] = j; ++cnt; }
        }
    }
    __syncthreads();
    int* pp = perm + (size_t)g * S_;
    for (int i = 0; i < 16; ++i) pp[tid + 256 * i] = ps[tid + 256 * i];
}

// ---------------------------------------------------------------------------
// FUSED LSH attention: per (g, chunk): MFMA dots (bf16), p = exp(dots - M_t),
// atomic D += rowsum(p), O = P@V via MFMA, atomic U += O.
// Round-softmax weighting cancels algebraically: lsh = U / D.
// LDS: phase1 Ks[128][72]; phase2 (union) P[64][136] + Vt[64][136].
// ---------------------------------------------------------------------------
__global__ __launch_bounds__(256)
void fused_attn(const unsigned short* __restrict__ qb,
                const unsigned short* __restrict__ vb,
                const int* __restrict__ perm,
                const float* __restrict__ qnorm,
                float* __restrict__ U, float* __restrict__ Dbuf) {
    __shared__ __align__(16) char smem[34816];
    unsigned short (*Ks)[72]  = (unsigned short (*)[72])smem;
    unsigned short (*P)[136]  = (unsigned short (*)[136])smem;
    unsigned short (*Vt)[136] = (unsigned short (*)[136])(smem + 17408);
    __shared__ int   toks[128];
    __shared__ float rk[128];
    __shared__ float qn_s[64];

    const int tid = threadIdx.x;
    const int g = blockIdx.y, c = blockIdx.x;
    const int bh = g >> 2;
    const int pc = (c + 63) & 63;
    const size_t gS = (size_t)g * S_, bhS = (size_t)bh * S_;

    if (tid < 128) {
        toks[tid] = (tid < 64) ? perm[gS + c * 64 + tid]
                               : perm[gS + pc * 64 + (tid - 64)];
    }
    __syncthreads();
    if (tid < 128) {
        float qn = qnorm[bhS + toks[tid]];
        rk[tid] = SCALE_ / (qn + 1e-6f);
        if (tid < 64) qn_s[tid] = SCALE_ * qn;
    }
    // stage K (raw bf16 q rows of all 128 tokens; queries are rows 0..63)
#pragma unroll
    for (int i = 0; i < 4; ++i) {
        int cc = tid + 256 * i;
        int row = cc >> 3, sub = cc & 7;
        ushort8 v = *reinterpret_cast<const ushort8*>(&qb[(bhS + toks[row]) * 64 + sub * 8]);
        *reinterpret_cast<ushort8*>(&Ks[row][sub * 8]) = v;
    }
    __syncthreads();

    const int lane = tid & 63, w = tid >> 6;
    const int l15 = lane & 15, l4 = lane >> 4;

    // dots: 16 rows (queries) x 128 cols (keys) per wave
    f32x4 accd[8];
#pragma unroll
    for (int fn = 0; fn < 8; ++fn) accd[fn] = (f32x4)0.f;
#pragma unroll
    for (int ks = 0; ks < 2; ++ks) {
        bf16x8 a = *reinterpret_cast<const bf16x8*>(&Ks[w * 16 + l15][l4 * 8 + ks * 32]);
#pragma unroll
        for (int fn = 0; fn < 8; ++fn) {
            bf16x8 b = *reinterpret_cast<const bf16x8*>(&Ks[fn * 16 + l15][l4 * 8 + ks * 32]);
            accd[fn] = __builtin_amdgcn_mfma_f32_16x16x32_bf16(a, b, accd[fn], 0, 0, 0);
        }
    }
    __syncthreads();   // all Ks reads done; LDS reused for P/Vt

    // p = exp(dots*0.125*rn_j - 0.125*qn_i); store P bf16; D row-sums
    float dsum[4] = {0.f, 0.f, 0.f, 0.f};
#pragma unroll
    for (int fn = 0; fn < 8; ++fn) {
        int j = fn * 16 + l15;
        float rj = rk[j];
#pragma unroll
        for (int q = 0; q < 4; ++q) {
            int i = w * 16 + l4 * 4 + q;
            float p = __expf(accd[fn][q] * rj - qn_s[i]);
            dsum[q] += p;
            P[i][j] = f2bf(p);
        }
    }
#pragma unroll
    for (int q = 0; q < 4; ++q) {
#pragma unroll
        for (int off = 1; off < 16; off <<= 1) dsum[q] += __shfl_xor(dsum[q], off);
    }
    if (l15 == 0) {
#pragma unroll
        for (int q = 0; q < 4; ++q)
            atomicAdd(&Dbuf[bhS + toks[w * 16 + l4 * 4 + q]], dsum[q]);
    }
    // stage V transposed: Vt[dh][tok]
#pragma unroll
    for (int i = 0; i < 4; ++i) {
        int cc = tid + 256 * i;
        int row = cc >> 3, sub = cc & 7;
        ushort8 v = *reinterpret_cast<const ushort8*>(&vb[(bhS + toks[row]) * 64 + sub * 8]);
#pragma unroll
        for (int e = 0; e < 8; ++e) Vt[sub * 8 + e][row] = v[e];
    }
    __syncthreads();

    // O = P @ V : 16 rows x 64 dh per wave, K = 128 tokens
    f32x4 acco[4];
#pragma unroll
    for (int fn = 0; fn < 4; ++fn) acco[fn] = (f32x4)0.f;
#pragma unroll
    for (int ks = 0; ks < 4; ++ks) {
        bf16x8 a = *reinterpret_cast<const bf16x8*>(&P[w * 16 + l15][l4 * 8 + ks * 32]);
#pragma unroll
        for (int fn = 0; fn < 4; ++fn) {
            bf16x8 b = *reinterpret_cast<const bf16x8*>(&Vt[fn * 16 + l15][l4 * 8 + ks * 32]);
            acco[fn] = __builtin_amdgcn_mfma_f32_16x16x32_bf16(a, b, acco[fn], 0, 0, 0);
        }
    }
#pragma unroll
    for (int fn = 0; fn < 4; ++fn) {
        int dh = fn * 16 + l15;
#pragma unroll
        for (int q = 0; q < 4; ++q) {
            int i = w * 16 + l4 * 4 + q;
            atomicAdd(&U[(bhS + toks[i]) * 64 + dh], acco[fn][q]);
        }
    }
}

// ---------------------------------------------------------------------------
// Local window attention + gate + mix. bf16 q/v inputs; lsh = U/D.
// Writes mixb bf16 flat (B,S,D).
// ---------------------------------------------------------------------------
__global__ __launch_bounds__(256)
void mix_kernel(const unsigned short* __restrict__ qb, const float* __restrict__ qnorm,
                const unsigned short* __restrict__ vb,
                const float* __restrict__ U, const float* __restrict__ Dbuf,
                const float* __restrict__ w_gate, const float* __restrict__ b_gate,
                unsigned short* __restrict__ mixb, float* __restrict__ gpart) {
    __shared__ float gacc[4];
    int tid = threadIdx.x, wv = tid >> 6, lane = tid & 63;
    int row = blockIdx.x * 4 + wv;       // bh*S + s
    int s = row & (S_ - 1);
    int bh = row >> 12;
    int h = bh & 15, b = bh >> 4;
    float qd = bf2f(qb[(size_t)row * 64 + lane]);
    float pw[9], vbv[9];
#pragma unroll
    for (int w = 0; w < 9; ++w) {
        int idx = s - 4 + w;
        bool valid = (idx >= 0) && (idx < S_);
        int ic = idx < 0 ? 0 : (idx >= S_ ? S_ - 1 : idx);
        size_t rr = (size_t)bh * S_ + ic;
        float kk = bf2f(qb[rr * 64 + lane]);
        float p = qd * kk;
#pragma unroll
        for (int off = 32; off; off >>= 1) p += __shfl_xor(p, off);
        float rn = 1.f / (qnorm[rr] + 1e-6f);
        pw[w] = valid ? p * rn * SCALE_ : -1e9f;
        vbv[w] = bf2f(vb[rr * 64 + lane]);
    }
    float mx = pw[0];
#pragma unroll
    for (int w = 1; w < 9; ++w) mx = fmaxf(mx, pw[w]);
    float den = 0.f, loc = 0.f;
#pragma unroll
    for (int w = 0; w < 9; ++w) { float e = __expf(pw[w] - mx); den += e; loc += e * vbv[w]; }
    loc /= den;
    float gv = qd * w_gate[h * 64 + lane];
#pragma unroll
    for (int off = 32; off; off >>= 1) gv += __shfl_xor(gv, off);
    float gg = sigf(gv + b_gate[h]);
    float lv = U[(size_t)row * 64 + lane] / Dbuf[row];
    float mval = gg * loc + (1.f - gg) * lv;
    mixb[((size_t)b * S_ + s) * 1024 + h * 64 + lane] = f2bf(mval);
    if (lane == 0) gacc[wv] = gg * (1.f - gg);
    __syncthreads();
    if (tid == 0) gpart[blockIdx.x] = gacc[0] + gacc[1] + gacc[2] + gacc[3];
}

__global__ __launch_bounds__(256)
void reg_reduce(const float* __restrict__ gpart, float* __restrict__ outreg) {
    __shared__ float part[4];
    float sm = 0.f;
    for (int i = threadIdx.x; i < 32768; i += 256) sm += gpart[i];
#pragma unroll
    for (int off = 32; off; off >>= 1) sm += __shfl_xor(sm, off);
    if ((threadIdx.x & 63) == 0) part[threadIdx.x >> 6] = sm;
    __syncthreads();
    if (threadIdx.x == 0) outreg[0] = (part[0] + part[1] + part[2] + part[3]) * (1.f / 131072.f);
}

// ---------------------------------------------------------------------------
// LayerNorm over D=1024, block per row; bf16 out
// ---------------------------------------------------------------------------
__global__ __launch_bounds__(256)
void ln_kernel(const float* __restrict__ x, const float* __restrict__ gg,
               const float* __restrict__ bb, unsigned short* __restrict__ outp) {
    __shared__ float ps[4][2];
    int row = blockIdx.x, tid = threadIdx.x;
    int wv = tid >> 6, lane = tid & 63;
    const float* xr = x + (size_t)row * 1024;
    float4 xv = *reinterpret_cast<const float4*>(&xr[tid * 4]);
    float s = xv.x + xv.y + xv.z + xv.w;
    float s2 = xv.x * xv.x + xv.y * xv.y + xv.z * xv.z + xv.w * xv.w;
#pragma unroll
    for (int off = 32; off; off >>= 1) { s += __shfl_xor(s, off); s2 += __shfl_xor(s2, off); }
    if (lane == 0) { ps[wv][0] = s; ps[wv][1] = s2; }
    __syncthreads();
    s  = ps[0][0] + ps[1][0] + ps[2][0] + ps[3][0];
    s2 = ps[0][1] + ps[1][1] + ps[2][1] + ps[3][1];
    float mean = s * (1.f / 1024.f);
    float var = s2 * (1.f / 1024.f) - mean * mean;
    float rs = rsqrtf(var + 1e-5f);
    float4 gv = *reinterpret_cast<const float4*>(&gg[tid * 4]);
    float4 bv = *reinterpret_cast<const float4*>(&bb[tid * 4]);
    ushort4v o;
    o[0] = f2bf((xv.x - mean) * rs * gv.x + bv.x);
    o[1] = f2bf((xv.y - mean) * rs * gv.y + bv.y);
    o[2] = f2bf((xv.z - mean) * rs * gv.z + bv.z);
    o[3] = f2bf((xv.w - mean) * rs * gv.w + bv.w);
    *reinterpret_cast<ushort4v*>(&outp[(size_t)row * 1024 + tid * 4]) = o;
}

// ---------------------------------------------------------------------------
// ws layout (62.0 MB, < 63.57 known-good):
//  A 0:        x2b -> qb -> tb            (16.8 MB)
//  B 16777216: v_bf16 -> hb              (16.8 MB)
//  C 33554432: buckets (2MB) then mixb   (16.8 MB)
//  D 50331648: WvT/WoT/W1T/W2T           (4 x 2 MB)
//  E 58720256: perm                      (2 MB)
//  F 60817408: qnorm                     (0.5 MB)
//  G 61341696: Dbuf                      (0.5 MB)
//  H 61865984: gpart                     (128 KB)
// d_out: [0] qk -> y1; [BSD] U-accum -> y2; [2BSD] reg
// ---------------------------------------------------------------------------
extern "C" void kernel_launch(void* const* d_in, const int* in_sizes, int n_in,
                              void* d_out, int out_size, void* d_ws, size_t ws_size,
                              hipStream_t stream) {
    (void)in_sizes; (void)n_in; (void)out_size; (void)ws_size;
    const float* x1    = (const float*)d_in[0];
    const float* x2    = (const float*)d_in[1];
    const float* Wqk   = (const float*)d_in[2];
    const float* Wv    = (const float*)d_in[3];
    const float* Wo    = (const float*)d_in[4];
    const float* rot   = (const float*)d_in[5];
    const float* w_gate= (const float*)d_in[6];
    const float* b_gate= (const float*)d_in[7];
    const float* ln_g  = (const float*)d_in[8];
    const float* ln_b  = (const float*)d_in[9];
    const float* W1    = (const float*)d_in[10];
    const float* b1    = (const float*)d_in[11];
    const float* W2    = (const float*)d_in[12];
    const float* b2    = (const float*)d_in[13];
    const float* alpha = (const float*)d_in[14];
    const float* beta  = (const float*)d_in[15];

    float* out = (float*)d_out;
    float* qk  = out;                       // -> y1
    float* Ubuf= out + (size_t)BSD_;        // -> y2
    float* y1  = out;
    float* y2  = out + (size_t)BSD_;

    char* ws = (char*)d_ws;
    unsigned short* x2b   = (unsigned short*)(ws + 0);
    unsigned short* qb    = (unsigned short*)(ws + 0);
    unsigned short* tb    = (unsigned short*)(ws + 0);
    unsigned short* vbuf  = (unsigned short*)(ws + 16777216);
    unsigned short* hb    = (unsigned short*)(ws + 16777216);
    int*   buckets        = (int*)  (ws + 33554432);
    unsigned short* mixb  = (unsigned short*)(ws + 33554432);
    unsigned short* WvT   = (unsigned short*)(ws + 50331648);
    unsigned short* WoT   = (unsigned short*)(ws + 52428800);
    unsigned short* W1T   = (unsigned short*)(ws + 54525952);
    unsigned short* W2T   = (unsigned short*)(ws + 56623104);
    int*   perm           = (int*)  (ws + 58720256);
    float* qnorm          = (float*)(ws + 60817408);
    float* Dbuf           = (float*)(ws + 61341696);
    float* gpart          = (float*)(ws + 61865984);

    hipMemsetAsync(Ubuf, 0, (size_t)BSD_ * sizeof(float), stream);
    hipMemsetAsync(Dbuf, 0, 131072 * sizeof(float), stream);

    dim3 gg(8, 64), gb(256);
    f2bf_kernel<<<4096, 256, 0, stream>>>(x2, x2b);
    wtrans_kernel<<<dim3(32, 32), 256, 0, stream>>>(Wv, WvT);
    wtrans_kernel<<<dim3(32, 32), 256, 0, stream>>>(Wo, WoT);
    wtrans_kernel<<<dim3(32, 32), 256, 0, stream>>>(W1, W1T);
    wtrans_kernel<<<dim3(32, 32), 256, 0, stream>>>(W2, W2T);

    gemm_f32_qk<<<gg, gb, 0, stream>>>(x2, Wqk, qk);                       // fp32 (buckets!)
    gemm_bf16<0><<<gg, gb, 0, stream>>>(x2b, WvT, vbuf, nullptr, nullptr, nullptr);

    stage_kernel<<<32768, 256, 0, stream>>>(qk, qb, qnorm);
    buckets_kernel<<<dim3(16, 128), 256, 0, stream>>>(qk, rot, buckets);
    sort_kernel<<<128, 256, 0, stream>>>(buckets, perm);

    fused_attn<<<dim3(64, 128), 256, 0, stream>>>(qb, vbuf, perm, qnorm, Ubuf, Dbuf);

    mix_kernel<<<32768, 256, 0, stream>>>(qb, qnorm, vbuf, Ubuf, Dbuf,
                                          w_gate, b_gate, mixb, gpart);
    reg_reduce<<<1, 256, 0, stream>>>(gpart, out + 2 * (size_t)BSD_);

    gemm_bf16<1><<<gg, gb, 0, stream>>>(mixb, WoT, y1, nullptr, x1, alpha);
    ln_kernel<<<8192, 256, 0, stream>>>(y1, ln_g, ln_b, hb);
    gemm_bf16<2><<<gg, gb, 0, stream>>>(hb, W1T, tb, b1, nullptr, nullptr);
    gemm_bf16<3><<<gg, gb, 0, stream>>>(tb, W2T, y2, b2, x2, beta);
}

// Round 5
// 772.240 us; speedup vs baseline: 3.2667x; 1.3507x over previous
//
#include <hip/hip_runtime.h>
#include <math.h>

#define B_    2
#define S_    4096
#define D_    1024
#define H_    16
#define DH_   64
#define NH_   4
#define BSD_  8388608     // B*S*D
#define SCALE_ 0.125f     // DH^-0.5

typedef __attribute__((ext_vector_type(8))) short   bf16x8;   // 8 bf16 (4 VGPR)
typedef __attribute__((ext_vector_type(4))) float   f32x4;
typedef __attribute__((ext_vector_type(8))) unsigned short ushort8;
typedef __attribute__((ext_vector_type(4))) unsigned short ushort4v;

__device__ __forceinline__ float sigf(float x) { return 1.f / (1.f + expf(-x)); }

__device__ __forceinline__ unsigned short f2bf(float f) {   // RNE float->bf16 bits
    union { float f; unsigned u; } v; v.f = f;
    unsigned r = v.u + 0x7FFF + ((v.u >> 16) & 1);
    return (unsigned short)(r >> 16);
}
__device__ __forceinline__ float bf2f(unsigned short u) {
    union { unsigned u; float f; } v; v.u = ((unsigned)u) << 16; return v.f;
}

__device__ __forceinline__ void gload_lds16(const void* g, void* l) {
    __builtin_amdgcn_global_load_lds(
        (const __attribute__((address_space(1))) void*)(g),
        (__attribute__((address_space(3))) void*)(l),
        16, 0, 0);
}

// ---------------------------------------------------------------------------
// fp32 GEMM (Wqk only -- bucket argmax needs fp32): C = A @ W,
// out head-layout [((b*H+h)*S+s)*64+dh]
// ---------------------------------------------------------------------------
__global__ __launch_bounds__(256)
void gemm_f32_qk(const float* __restrict__ A, const float* __restrict__ W,
                 float* __restrict__ out) {
    const int K = 1024, N = 1024;
    __shared__ float As[16][129];
    __shared__ float Bs[16][128];
    const int tid = threadIdx.x;
    const int ty = tid >> 4, tx = tid & 15;
    const int m0 = blockIdx.y * 128, n0 = blockIdx.x * 128;

    float acc[8][8];
#pragma unroll
    for (int i = 0; i < 8; ++i)
#pragma unroll
        for (int j = 0; j < 8; ++j) acc[i][j] = 0.f;

    for (int kt = 0; kt < K; kt += 16) {
#pragma unroll
        for (int l = 0; l < 2; ++l) {
            int cid = tid + l * 256;
            int r  = cid >> 2, c4 = (cid & 3) << 2;
            float4 a4 = *reinterpret_cast<const float4*>(&A[(size_t)(m0 + r) * K + kt + c4]);
            As[c4 + 0][r] = a4.x; As[c4 + 1][r] = a4.y;
            As[c4 + 2][r] = a4.z; As[c4 + 3][r] = a4.w;
            int r2 = cid >> 5, c42 = (cid & 31) << 2;
            *reinterpret_cast<float4*>(&Bs[r2][c42]) =
                *reinterpret_cast<const float4*>(&W[(size_t)(kt + r2) * N + n0 + c42]);
        }
        __syncthreads();
#pragma unroll
        for (int kk = 0; kk < 16; ++kk) {
            float a[8], b[8];
#pragma unroll
            for (int i = 0; i < 8; ++i) a[i] = As[kk][ty * 8 + i];
            float4 b0 = *reinterpret_cast<float4*>(&Bs[kk][tx * 8]);
            float4 b1 = *reinterpret_cast<float4*>(&Bs[kk][tx * 8 + 4]);
            b[0] = b0.x; b[1] = b0.y; b[2] = b0.z; b[3] = b0.w;
            b[4] = b1.x; b[5] = b1.y; b[6] = b1.z; b[7] = b1.w;
#pragma unroll
            for (int i = 0; i < 8; ++i)
#pragma unroll
                for (int j = 0; j < 8; ++j) acc[i][j] += a[i] * b[j];
        }
        __syncthreads();
    }
#pragma unroll
    for (int i = 0; i < 8; ++i) {
        int m = m0 + ty * 8 + i;
        int bb = m >> 12, s = m & 4095;
        int n = n0 + tx * 8;
        int h = n >> 6, dh = n & 63;
        float* op = out + ((((size_t)bb * H_ + h) * S_ + s) << 6) + dh;
        *reinterpret_cast<float4*>(op)     = make_float4(acc[i][0], acc[i][1], acc[i][2], acc[i][3]);
        *reinterpret_cast<float4*>(op + 4) = make_float4(acc[i][4], acc[i][5], acc[i][6], acc[i][7]);
    }
}

// ---------------------------------------------------------------------------
// bf16 MFMA GEMM, 128x128 tile, BK=32, 4 waves x (64x64 quadrant).
// MODE 0: out bf16 head-layout                       (v = x2 @ Wv)
// MODE 1: out fp32 = resid + sigf(gate[n]) * acc     (y1)
// MODE 2: out bf16 = relu(acc + bias[n])             (t)
// MODE 3: out fp32 = resid + sigf(gate[n])*(acc+bias)(y2)
// ---------------------------------------------------------------------------
template<int MODE>
__global__ __launch_bounds__(256)
void gemm_bf16(const unsigned short* __restrict__ A,
               const unsigned short* __restrict__ BT,
               void* __restrict__ outv,
               const float* __restrict__ bias,
               const float* __restrict__ resid,
               const float* __restrict__ gatev) {
    __shared__ __align__(16) unsigned short Als[128 * 32];
    __shared__ __align__(16) unsigned short Bls[128 * 32];
    const int tid = threadIdx.x;
    const int lane = tid & 63, w = tid >> 6;
    const int wr = w >> 1, wc = w & 1;
    const int m0 = blockIdx.y * 128, n0 = blockIdx.x * 128;
    const int l15 = lane & 15, l4 = lane >> 4;

    f32x4 acc[4][4];
#pragma unroll
    for (int i = 0; i < 4; ++i)
#pragma unroll
        for (int j = 0; j < 4; ++j) acc[i][j] = (f32x4)0.f;

    for (int kt = 0; kt < 1024; kt += 32) {
#pragma unroll
        for (int i = 0; i < 2; ++i) {
            int d = i * 256 + tid;
            int r = d >> 2, sl = d & 3;
            gload_lds16(&A [(size_t)(m0 + r) * 1024 + kt + sl * 8], &Als[(size_t)d * 8]);
            gload_lds16(&BT[(size_t)(n0 + r) * 1024 + kt + sl * 8], &Bls[(size_t)d * 8]);
        }
        __syncthreads();
        bf16x8 af[4], bfr[4];
#pragma unroll
        for (int f = 0; f < 4; ++f) {
            af[f]  = *reinterpret_cast<const bf16x8*>(&Als[(size_t)(wr * 64 + f * 16 + l15) * 32 + l4 * 8]);
            bfr[f] = *reinterpret_cast<const bf16x8*>(&Bls[(size_t)(wc * 64 + f * 16 + l15) * 32 + l4 * 8]);
        }
#pragma unroll
        for (int fm = 0; fm < 4; ++fm)
#pragma unroll
            for (int fn = 0; fn < 4; ++fn)
                acc[fm][fn] = __builtin_amdgcn_mfma_f32_16x16x32_bf16(af[fm], bfr[fn], acc[fm][fn], 0, 0, 0);
        __syncthreads();
    }

#pragma unroll
    for (int fn = 0; fn < 4; ++fn) {
        int n = n0 + wc * 64 + fn * 16 + l15;
        float sg = 0.f, bs = 0.f;
        if (MODE == 1) sg = sigf(gatev[n]);
        if (MODE == 2) bs = bias[n];
        if (MODE == 3) { sg = sigf(gatev[n]); bs = bias[n]; }
#pragma unroll
        for (int fm = 0; fm < 4; ++fm) {
#pragma unroll
            for (int q = 0; q < 4; ++q) {
                int m = m0 + wr * 64 + fm * 16 + l4 * 4 + q;
                float v = acc[fm][fn][q];
                if (MODE == 0) {
                    int bb = m >> 12, s = m & 4095;
                    int h = n >> 6, dh = n & 63;
                    ((unsigned short*)outv)[((((size_t)bb * H_ + h) * S_ + s) << 6) + dh] = f2bf(v);
                } else if (MODE == 1) {
                    size_t idx = (size_t)m * 1024 + n;
                    ((float*)outv)[idx] = resid[idx] + sg * v;
                } else if (MODE == 2) {
                    ((unsigned short*)outv)[(size_t)m * 1024 + n] = f2bf(fmaxf(v + bs, 0.f));
                } else {
                    size_t idx = (size_t)m * 1024 + n;
                    ((float*)outv)[idx] = resid[idx] + sg * (v + bs);
                }
            }
        }
    }
}

// ---------------------------------------------------------------------------
// fp32 -> bf16 elementwise (x2 copy)
// ---------------------------------------------------------------------------
__global__ __launch_bounds__(256)
void f2bf_kernel(const float* __restrict__ in, unsigned short* __restrict__ out) {
    size_t i = ((size_t)blockIdx.x * 256 + threadIdx.x) * 8;
    float4 a = *reinterpret_cast<const float4*>(&in[i]);
    float4 b = *reinterpret_cast<const float4*>(&in[i + 4]);
    ushort8 o;
    o[0] = f2bf(a.x); o[1] = f2bf(a.y); o[2] = f2bf(a.z); o[3] = f2bf(a.w);
    o[4] = f2bf(b.x); o[5] = f2bf(b.y); o[6] = f2bf(b.z); o[7] = f2bf(b.w);
    *reinterpret_cast<ushort8*>(&out[i]) = o;
}

// ---------------------------------------------------------------------------
// Weight transpose + convert: W(K,N) f32 -> WT(N,K) bf16
// ---------------------------------------------------------------------------
__global__ __launch_bounds__(256)
void wtrans_kernel(const float* __restrict__ W, unsigned short* __restrict__ WT) {
    __shared__ float tile[32][33];
    int n0 = blockIdx.x * 32, k0 = blockIdx.y * 32;
    int lx = threadIdx.x & 31, ly = threadIdx.x >> 5;
#pragma unroll
    for (int i = 0; i < 4; ++i)
        tile[ly + i * 8][lx] = W[(size_t)(k0 + ly + i * 8) * 1024 + n0 + lx];
    __syncthreads();
#pragma unroll
    for (int i = 0; i < 4; ++i)
        WT[(size_t)(n0 + ly + i * 8) * 1024 + k0 + lx] = f2bf(tile[lx][ly + i * 8]);
}

// ---------------------------------------------------------------------------
// stage: per row, qnorm[row] = |q|, qb = bf16(q) (head layout). Wave per row.
// ---------------------------------------------------------------------------
__global__ __launch_bounds__(256)
void stage_kernel(const float* __restrict__ qk, unsigned short* __restrict__ qb,
                  float* __restrict__ qnorm) {
    int tid = threadIdx.x, wv = tid >> 6, lane = tid & 63;
    int row = blockIdx.x * 4 + wv;
    float q = qk[(size_t)row * 64 + lane];
    float ss = q * q;
#pragma unroll
    for (int off = 32; off; off >>= 1) ss += __shfl_xor(ss, off);
    if (lane == 0) qnorm[row] = sqrtf(ss);
    qb[(size_t)row * 64 + lane] = f2bf(q);
}

// ---------------------------------------------------------------------------
// buckets: rot slice staged in LDS (8 KB), broadcast float4 reads.
// Accumulation order identical to previous version (bit-identical results).
// ---------------------------------------------------------------------------
__global__ __launch_bounds__(256)
void buckets_kernel(const float* __restrict__ qk, const float* __restrict__ rot,
                    int* __restrict__ buckets) {
    __shared__ __align__(16) float rs[64][32];   // [d][m], 8 KB
    int g = blockIdx.y;                  // (b*H+h)*4 + r, 0..127
    int r = g & 3;
    int bh = g >> 2;
    int h = bh & 15;
    const float* rbase = rot + (size_t)(h * NH_ + r) * 64 * 32;
    for (int i = threadIdx.x; i < 512; i += 256)
        *reinterpret_cast<float4*>(&rs[0][0] + (size_t)i * 4) =
            *reinterpret_cast<const float4*>(rbase + (size_t)i * 4);
    __syncthreads();

    int tok = blockIdx.x * 256 + threadIdx.x;
    const float* qrow = qk + ((size_t)bh * S_ + tok) * 64;

    float rotd[32];
#pragma unroll
    for (int m = 0; m < 32; ++m) rotd[m] = 0.f;
#pragma unroll
    for (int d4 = 0; d4 < 16; ++d4) {
        float4 q4 = *reinterpret_cast<const float4*>(qrow + (d4 << 2));
#pragma unroll
        for (int mm = 0; mm < 8; ++mm) {
            float4 r0 = *reinterpret_cast<const float4*>(&rs[d4 * 4 + 0][mm * 4]);
            float4 r1 = *reinterpret_cast<const float4*>(&rs[d4 * 4 + 1][mm * 4]);
            float4 r2 = *reinterpret_cast<const float4*>(&rs[d4 * 4 + 2][mm * 4]);
            float4 r3 = *reinterpret_cast<const float4*>(&rs[d4 * 4 + 3][mm * 4]);
            rotd[mm * 4 + 0] += q4.x * r0.x + q4.y * r1.x + q4.z * r2.x + q4.w * r3.x;
            rotd[mm * 4 + 1] += q4.x * r0.y + q4.y * r1.y + q4.z * r2.y + q4.w * r3.y;
            rotd[mm * 4 + 2] += q4.x * r0.z + q4.y * r1.z + q4.z * r2.z + q4.w * r3.z;
            rotd[mm * 4 + 3] += q4.x * r0.w + q4.y * r1.w + q4.z * r2.w + q4.w * r3.w;
        }
    }
    float bv = rotd[0]; int bi = 0;
#pragma unroll
    for (int m = 1; m < 32; ++m) if (rotd[m] > bv) { bv = rotd[m]; bi = m; }
#pragma unroll
    for (int m = 0; m < 32; ++m) { float nv = -rotd[m]; if (nv > bv) { bv = nv; bi = 32 + m; } }
    buckets[(size_t)g * S_ + tok] = bi;
}

// ---------------------------------------------------------------------------
// Stable counting sort per group g: perm = argsort(bucket*S + pos)
// ---------------------------------------------------------------------------
__global__ __launch_bounds__(256)
void sort_kernel(const int* __restrict__ buckets, int* __restrict__ perm) {
    __shared__ int bk[4096];
    __shared__ int qcnt[4][64];
    __shared__ int qoff[4][64];
    __shared__ int ps[4096];
    int g = blockIdx.x, tid = threadIdx.x;
    const int* bp = buckets + (size_t)g * S_;
    for (int i = 0; i < 16; ++i) bk[tid + 256 * i] = bp[tid + 256 * i];
    qcnt[tid >> 6][tid & 63] = 0;
    __syncthreads();
    int q = tid >> 6, l = tid & 63;
    for (int i = 0; i < 16; ++i) {
        int pos = q * 1024 + l + 64 * i;
        atomicAdd(&qcnt[q][bk[pos]], 1);
    }
    __syncthreads();
    if (tid == 0) {
        int run = 0;
        for (int b = 0; b < 64; ++b)
            for (int qq = 0; qq < 4; ++qq) { qoff[qq][b] = run; run += qcnt[qq][b]; }
    }
    __syncthreads();
    {
        int base = qoff[q][l], cnt = 0;
        for (int j = q * 1024; j < q * 1024 + 1024; ++j) {
            if (bk[j] == l) { ps[base + cnt] = j; ++cnt; }
        }
    }
    __syncthreads();
    int* pp = perm + (size_t)g * S_;
    for (int i = 0; i < 16; ++i) pp[tid + 256 * i] = ps[tid + 256 * i];
}

// ---------------------------------------------------------------------------
// FUSED LSH attention: per (g, chunk): MFMA dots (bf16), p = exp(dots - M_t),
// atomic D += rowsum(p), O = P@V via MFMA, atomic U += O.
// ---------------------------------------------------------------------------
__global__ __launch_bounds__(256)
void fused_attn(const unsigned short* __restrict__ qb,
                const unsigned short* __restrict__ vb,
                const int* __restrict__ perm,
                const float* __restrict__ qnorm,
                float* __restrict__ U, float* __restrict__ Dbuf) {
    __shared__ __align__(16) char smem[34816];
    unsigned short (*Ks)[72]  = (unsigned short (*)[72])smem;
    unsigned short (*P)[136]  = (unsigned short (*)[136])smem;
    unsigned short (*Vt)[136] = (unsigned short (*)[136])(smem + 17408);
    __shared__ int   toks[128];
    __shared__ float rk[128];
    __shared__ float qn_s[64];

    const int tid = threadIdx.x;
    const int g = blockIdx.y, c = blockIdx.x;
    const int bh = g >> 2;
    const int pc = (c + 63) & 63;
    const size_t gS = (size_t)g * S_, bhS = (size_t)bh * S_;

    if (tid < 128) {
        toks[tid] = (tid < 64) ? perm[gS + c * 64 + tid]
                               : perm[gS + pc * 64 + (tid - 64)];
    }
    __syncthreads();
    if (tid < 128) {
        float qn = qnorm[bhS + toks[tid]];
        rk[tid] = SCALE_ / (qn + 1e-6f);
        if (tid < 64) qn_s[tid] = SCALE_ * qn;
    }
#pragma unroll
    for (int i = 0; i < 4; ++i) {
        int cc = tid + 256 * i;
        int row = cc >> 3, sub = cc & 7;
        ushort8 v = *reinterpret_cast<const ushort8*>(&qb[(bhS + toks[row]) * 64 + sub * 8]);
        *reinterpret_cast<ushort8*>(&Ks[row][sub * 8]) = v;
    }
    __syncthreads();

    const int lane = tid & 63, w = tid >> 6;
    const int l15 = lane & 15, l4 = lane >> 4;

    f32x4 accd[8];
#pragma unroll
    for (int fn = 0; fn < 8; ++fn) accd[fn] = (f32x4)0.f;
#pragma unroll
    for (int ks = 0; ks < 2; ++ks) {
        bf16x8 a = *reinterpret_cast<const bf16x8*>(&Ks[w * 16 + l15][l4 * 8 + ks * 32]);
#pragma unroll
        for (int fn = 0; fn < 8; ++fn) {
            bf16x8 b = *reinterpret_cast<const bf16x8*>(&Ks[fn * 16 + l15][l4 * 8 + ks * 32]);
            accd[fn] = __builtin_amdgcn_mfma_f32_16x16x32_bf16(a, b, accd[fn], 0, 0, 0);
        }
    }
    __syncthreads();

    float dsum[4] = {0.f, 0.f, 0.f, 0.f};
#pragma unroll
    for (int fn = 0; fn < 8; ++fn) {
        int j = fn * 16 + l15;
        float rj = rk[j];
#pragma unroll
        for (int q = 0; q < 4; ++q) {
            int i = w * 16 + l4 * 4 + q;
            float p = __expf(accd[fn][q] * rj - qn_s[i]);
            dsum[q] += p;
            P[i][j] = f2bf(p);
        }
    }
#pragma unroll
    for (int q = 0; q < 4; ++q) {
#pragma unroll
        for (int off = 1; off < 16; off <<= 1) dsum[q] += __shfl_xor(dsum[q], off);
    }
    if (l15 == 0) {
#pragma unroll
        for (int q = 0; q < 4; ++q)
            atomicAdd(&Dbuf[bhS + toks[w * 16 + l4 * 4 + q]], dsum[q]);
    }
#pragma unroll
    for (int i = 0; i < 4; ++i) {
        int cc = tid + 256 * i;
        int row = cc >> 3, sub = cc & 7;
        ushort8 v = *reinterpret_cast<const ushort8*>(&vb[(bhS + toks[row]) * 64 + sub * 8]);
#pragma unroll
        for (int e = 0; e < 8; ++e) Vt[sub * 8 + e][row] = v[e];
    }
    __syncthreads();

    f32x4 acco[4];
#pragma unroll
    for (int fn = 0; fn < 4; ++fn) acco[fn] = (f32x4)0.f;
#pragma unroll
    for (int ks = 0; ks < 4; ++ks) {
        bf16x8 a = *reinterpret_cast<const bf16x8*>(&P[w * 16 + l15][l4 * 8 + ks * 32]);
#pragma unroll
        for (int fn = 0; fn < 4; ++fn) {
            bf16x8 b = *reinterpret_cast<const bf16x8*>(&Vt[fn * 16 + l15][l4 * 8 + ks * 32]);
            acco[fn] = __builtin_amdgcn_mfma_f32_16x16x32_bf16(a, b, acco[fn], 0, 0, 0);
        }
    }
#pragma unroll
    for (int fn = 0; fn < 4; ++fn) {
        int dh = fn * 16 + l15;
#pragma unroll
        for (int q = 0; q < 4; ++q) {
            int i = w * 16 + l4 * 4 + q;
            atomicAdd(&U[(bhS + toks[i]) * 64 + dh], acco[fn][q]);
        }
    }
}

// ---------------------------------------------------------------------------
// Local window attention + gate + mix. bf16 q/v inputs; lsh = U/D.
// ---------------------------------------------------------------------------
__global__ __launch_bounds__(256)
void mix_kernel(const unsigned short* __restrict__ qb, const float* __restrict__ qnorm,
                const unsigned short* __restrict__ vb,
                const float* __restrict__ U, const float* __restrict__ Dbuf,
                const float* __restrict__ w_gate, const float* __restrict__ b_gate,
                unsigned short* __restrict__ mixb, float* __restrict__ gpart) {
    __shared__ float gacc[4];
    int tid = threadIdx.x, wv = tid >> 6, lane = tid & 63;
    int row = blockIdx.x * 4 + wv;       // bh*S + s
    int s = row & (S_ - 1);
    int bh = row >> 12;
    int h = bh & 15, b = bh >> 4;
    float qd = bf2f(qb[(size_t)row * 64 + lane]);
    float pw[9], vbv[9];
#pragma unroll
    for (int w = 0; w < 9; ++w) {
        int idx = s - 4 + w;
        bool valid = (idx >= 0) && (idx < S_);
        int ic = idx < 0 ? 0 : (idx >= S_ ? S_ - 1 : idx);
        size_t rr = (size_t)bh * S_ + ic;
        float kk = bf2f(qb[rr * 64 + lane]);
        float p = qd * kk;
#pragma unroll
        for (int off = 32; off; off >>= 1) p += __shfl_xor(p, off);
        float rn = 1.f / (qnorm[rr] + 1e-6f);
        pw[w] = valid ? p * rn * SCALE_ : -1e9f;
        vbv[w] = bf2f(vb[rr * 64 + lane]);
    }
    float mx = pw[0];
#pragma unroll
    for (int w = 1; w < 9; ++w) mx = fmaxf(mx, pw[w]);
    float den = 0.f, loc = 0.f;
#pragma unroll
    for (int w = 0; w < 9; ++w) { float e = __expf(pw[w] - mx); den += e; loc += e * vbv[w]; }
    loc /= den;
    float gv = qd * w_gate[h * 64 + lane];
#pragma unroll
    for (int off = 32; off; off >>= 1) gv += __shfl_xor(gv, off);
    float gg = sigf(gv + b_gate[h]);
    float lv = U[(size_t)row * 64 + lane] / Dbuf[row];
    float mval = gg * loc + (1.f - gg) * lv;
    mixb[((size_t)b * S_ + s) * 1024 + h * 64 + lane] = f2bf(mval);
    if (lane == 0) gacc[wv] = gg * (1.f - gg);
    __syncthreads();
    if (tid == 0) gpart[blockIdx.x] = gacc[0] + gacc[1] + gacc[2] + gacc[3];
}

__global__ __launch_bounds__(256)
void reg_reduce(const float* __restrict__ gpart, float* __restrict__ outreg) {
    __shared__ float part[4];
    float sm = 0.f;
    for (int i = threadIdx.x; i < 32768; i += 256) sm += gpart[i];
#pragma unroll
    for (int off = 32; off; off >>= 1) sm += __shfl_xor(sm, off);
    if ((threadIdx.x & 63) == 0) part[threadIdx.x >> 6] = sm;
    __syncthreads();
    if (threadIdx.x == 0) outreg[0] = (part[0] + part[1] + part[2] + part[3]) * (1.f / 131072.f);
}

// ---------------------------------------------------------------------------
// LayerNorm over D=1024, block per row; bf16 out
// ---------------------------------------------------------------------------
__global__ __launch_bounds__(256)
void ln_kernel(const float* __restrict__ x, const float* __restrict__ gg,
               const float* __restrict__ bb, unsigned short* __restrict__ outp) {
    __shared__ float ps[4][2];
    int row = blockIdx.x, tid = threadIdx.x;
    int wv = tid >> 6, lane = tid & 63;
    const float* xr = x + (size_t)row * 1024;
    float4 xv = *reinterpret_cast<const float4*>(&xr[tid * 4]);
    float s = xv.x + xv.y + xv.z + xv.w;
    float s2 = xv.x * xv.x + xv.y * xv.y + xv.z * xv.z + xv.w * xv.w;
#pragma unroll
    for (int off = 32; off; off >>= 1) { s += __shfl_xor(s, off); s2 += __shfl_xor(s2, off); }
    if (lane == 0) { ps[wv][0] = s; ps[wv][1] = s2; }
    __syncthreads();
    s  = ps[0][0] + ps[1][0] + ps[2][0] + ps[3][0];
    s2 = ps[0][1] + ps[1][1] + ps[2][1] + ps[3][1];
    float mean = s * (1.f / 1024.f);
    float var = s2 * (1.f / 1024.f) - mean * mean;
    float rs = rsqrtf(var + 1e-5f);
    float4 gv = *reinterpret_cast<const float4*>(&gg[tid * 4]);
    float4 bv = *reinterpret_cast<const float4*>(&bb[tid * 4]);
    ushort4v o;
    o[0] = f2bf((xv.x - mean) * rs * gv.x + bv.x);
    o[1] = f2bf((xv.y - mean) * rs * gv.y + bv.y);
    o[2] = f2bf((xv.z - mean) * rs * gv.z + bv.z);
    o[3] = f2bf((xv.w - mean) * rs * gv.w + bv.w);
    *reinterpret_cast<ushort4v*>(&outp[(size_t)row * 1024 + tid * 4]) = o;
}

// ---------------------------------------------------------------------------
// ws layout (62.0 MB):
//  A 0:        x2b -> qb -> tb           (16.8 MB)
//  B 16777216: v_bf16 -> hb              (16.8 MB)
//  C 33554432: buckets (2MB) then mixb   (16.8 MB)
//  D 50331648: WvT/WoT/W1T/W2T           (4 x 2 MB)
//  E 58720256: perm                      (2 MB)
//  F 60817408: qnorm                     (0.5 MB)
//  G 61341696: Dbuf                      (0.5 MB)
//  H 61865984: gpart                     (128 KB)
// d_out: [0] qk -> y1; [BSD] U-accum -> y2; [2BSD] reg
// ---------------------------------------------------------------------------
extern "C" void kernel_launch(void* const* d_in, const int* in_sizes, int n_in,
                              void* d_out, int out_size, void* d_ws, size_t ws_size,
                              hipStream_t stream) {
    (void)in_sizes; (void)n_in; (void)out_size; (void)ws_size;
    const float* x1    = (const float*)d_in[0];
    const float* x2    = (const float*)d_in[1];
    const float* Wqk   = (const float*)d_in[2];
    const float* Wv    = (const float*)d_in[3];
    const float* Wo    = (const float*)d_in[4];
    const float* rot   = (const float*)d_in[5];
    const float* w_gate= (const float*)d_in[6];
    const float* b_gate= (const float*)d_in[7];
    const float* ln_g  = (const float*)d_in[8];
    const float* ln_b  = (const float*)d_in[9];
    const float* W1    = (const float*)d_in[10];
    const float* b1    = (const float*)d_in[11];
    const float* W2    = (const float*)d_in[12];
    const float* b2    = (const float*)d_in[13];
    const float* alpha = (const float*)d_in[14];
    const float* beta  = (const float*)d_in[15];

    float* out = (float*)d_out;
    float* qk  = out;                       // -> y1
    float* Ubuf= out + (size_t)BSD_;        // -> y2
    float* y1  = out;
    float* y2  = out + (size_t)BSD_;

    char* ws = (char*)d_ws;
    unsigned short* x2b   = (unsigned short*)(ws + 0);
    unsigned short* qb    = (unsigned short*)(ws + 0);
    unsigned short* tb    = (unsigned short*)(ws + 0);
    unsigned short* vbuf  = (unsigned short*)(ws + 16777216);
    unsigned short* hb    = (unsigned short*)(ws + 16777216);
    int*   buckets        = (int*)  (ws + 33554432);
    unsigned short* mixb  = (unsigned short*)(ws + 33554432);
    unsigned short* WvT   = (unsigned short*)(ws + 50331648);
    unsigned short* WoT   = (unsigned short*)(ws + 52428800);
    unsigned short* W1T   = (unsigned short*)(ws + 54525952);
    unsigned short* W2T   = (unsigned short*)(ws + 56623104);
    int*   perm           = (int*)  (ws + 58720256);
    float* qnorm          = (float*)(ws + 60817408);
    float* Dbuf           = (float*)(ws + 61341696);
    float* gpart          = (float*)(ws + 61865984);

    hipMemsetAsync(Ubuf, 0, (size_t)BSD_ * sizeof(float), stream);
    hipMemsetAsync(Dbuf, 0, 131072 * sizeof(float), stream);

    dim3 gg(8, 64), gb(256);
    f2bf_kernel<<<4096, 256, 0, stream>>>(x2, x2b);
    wtrans_kernel<<<dim3(32, 32), 256, 0, stream>>>(Wv, WvT);
    wtrans_kernel<<<dim3(32, 32), 256, 0, stream>>>(Wo, WoT);
    wtrans_kernel<<<dim3(32, 32), 256, 0, stream>>>(W1, W1T);
    wtrans_kernel<<<dim3(32, 32), 256, 0, stream>>>(W2, W2T);

    gemm_f32_qk<<<gg, gb, 0, stream>>>(x2, Wqk, qk);                       // fp32 (buckets!)
    gemm_bf16<0><<<gg, gb, 0, stream>>>(x2b, WvT, vbuf, nullptr, nullptr, nullptr);

    stage_kernel<<<32768, 256, 0, stream>>>(qk, qb, qnorm);
    buckets_kernel<<<dim3(16, 128), 256, 0, stream>>>(qk, rot, buckets);
    sort_kernel<<<128, 256, 0, stream>>>(buckets, perm);

    fused_attn<<<dim3(64, 128), 256, 0, stream>>>(qb, vbuf, perm, qnorm, Ubuf, Dbuf);

    mix_kernel<<<32768, 256, 0, stream>>>(qb, qnorm, vbuf, Ubuf, Dbuf,
                                          w_gate, b_gate, mixb, gpart);
    reg_reduce<<<1, 256, 0, stream>>>(gpart, out + 2 * (size_t)BSD_);

    gemm_bf16<1><<<gg, gb, 0, stream>>>(mixb, WoT, y1, nullptr, x1, alpha);
    ln_kernel<<<8192, 256, 0, stream>>>(y1, ln_g, ln_b, hb);
    gemm_bf16<2><<<gg, gb, 0, stream>>>(hb, W1T, tb, b1, nullptr, nullptr);
    gemm_bf16<3><<<gg, gb, 0, stream>>>(tb, W2T, y2, b2, x2, beta);
}

// Round 6
// 632.911 us; speedup vs baseline: 3.9858x; 1.2201x over previous
//
#include <hip/hip_runtime.h>
#include <math.h>

#define B_    2
#define S_    4096
#define D_    1024
#define H_    16
#define DH_   64
#define NH_   4
#define BSD_  8388608     // B*S*D
#define SCALE_ 0.125f     // DH^-0.5

typedef __attribute__((ext_vector_type(8))) short   bf16x8;   // 8 bf16 (4 VGPR)
typedef __attribute__((ext_vector_type(4))) float   f32x4;
typedef __attribute__((ext_vector_type(8))) unsigned short ushort8;
typedef __attribute__((ext_vector_type(4))) unsigned short ushort4v;

__device__ __forceinline__ float sigf(float x) { return 1.f / (1.f + expf(-x)); }

__device__ __forceinline__ unsigned short f2bf(float f) {   // RNE float->bf16 bits
    union { float f; unsigned u; } v; v.f = f;
    unsigned r = v.u + 0x7FFF + ((v.u >> 16) & 1);
    return (unsigned short)(r >> 16);
}
__device__ __forceinline__ float bf2f(unsigned short u) {
    union { unsigned u; float f; } v; v.u = ((unsigned)u) << 16; return v.f;
}

__device__ __forceinline__ void gload_lds16(const void* g, void* l) {
    __builtin_amdgcn_global_load_lds(
        (const __attribute__((address_space(1))) void*)(g),
        (__attribute__((address_space(3))) void*)(l),
        16, 0, 0);
}

// ---------------------------------------------------------------------------
// Split-precision qk GEMM: qk = x2 @ Wqk with near-fp32 accuracy via
// (hi+lo) bf16 decomposition and 4 MFMAs per fragment pair.
// hi = trunc16(x); lo = rne_bf16(x - hi); dropped error ~2^-17 per term.
// A (fp32) split in-kernel; W pre-split (BTh/BTl, N x K bf16).
// out fp32 head-layout [((b*H+h)*S+s)*64+dh].
// ---------------------------------------------------------------------------
__global__ __launch_bounds__(256)
void gemm_qk_split(const float* __restrict__ A,
                   const unsigned short* __restrict__ BTh,
                   const unsigned short* __restrict__ BTl,
                   float* __restrict__ out) {
    __shared__ __align__(16) unsigned short Ah[128 * 32];
    __shared__ __align__(16) unsigned short Al[128 * 32];
    __shared__ __align__(16) unsigned short Bh[128 * 32];
    __shared__ __align__(16) unsigned short Bl[128 * 32];
    const int tid = threadIdx.x;
    const int lane = tid & 63, w = tid >> 6;
    const int wr = w >> 1, wc = w & 1;
    const int m0 = blockIdx.y * 128, n0 = blockIdx.x * 128;
    const int l15 = lane & 15, lq = lane >> 4;

    f32x4 acc[4][4];
#pragma unroll
    for (int i = 0; i < 4; ++i)
#pragma unroll
        for (int j = 0; j < 4; ++j) acc[i][j] = (f32x4)0.f;

    for (int kt = 0; kt < 1024; kt += 32) {
        // B tiles (pre-split bf16) via async global->LDS
#pragma unroll
        for (int i = 0; i < 2; ++i) {
            int d = i * 256 + tid;               // 16B chunk 0..511
            int r = d >> 2, sl = d & 3;
            gload_lds16(&BTh[(size_t)(n0 + r) * 1024 + kt + sl * 8], &Bh[(size_t)d * 8]);
            gload_lds16(&BTl[(size_t)(n0 + r) * 1024 + kt + sl * 8], &Bl[(size_t)d * 8]);
        }
        // A tile: fp32 load -> hi/lo split -> LDS
#pragma unroll
        for (int i = 0; i < 4; ++i) {
            int ch = i * 256 + tid;              // float4 chunk 0..1023
            int r = ch >> 3, c = ch & 7;
            float4 a4 = *reinterpret_cast<const float4*>(&A[(size_t)(m0 + r) * 1024 + kt + c * 4]);
            float xs[4] = {a4.x, a4.y, a4.z, a4.w};
            ushort4v h4, lo4;
#pragma unroll
            for (int e = 0; e < 4; ++e) {
                union { float f; unsigned u; } vv; vv.f = xs[e];
                h4[e] = (unsigned short)(vv.u >> 16);           // trunc hi
                union { unsigned u; float f; } hb; hb.u = vv.u & 0xFFFF0000u;
                lo4[e] = f2bf(xs[e] - hb.f);                    // RNE lo
            }
            *reinterpret_cast<ushort4v*>(&Ah[(size_t)r * 32 + c * 4]) = h4;
            *reinterpret_cast<ushort4v*>(&Al[(size_t)r * 32 + c * 4]) = lo4;
        }
        __syncthreads();
        bf16x8 afh[4], afl[4], bfh[4], bfl[4];
#pragma unroll
        for (int f = 0; f < 4; ++f) {
            int ar = (wr * 64 + f * 16 + l15) * 32 + lq * 8;
            int br = (wc * 64 + f * 16 + l15) * 32 + lq * 8;
            afh[f] = *reinterpret_cast<const bf16x8*>(&Ah[ar]);
            afl[f] = *reinterpret_cast<const bf16x8*>(&Al[ar]);
            bfh[f] = *reinterpret_cast<const bf16x8*>(&Bh[br]);
            bfl[f] = *reinterpret_cast<const bf16x8*>(&Bl[br]);
        }
#pragma unroll
        for (int fm = 0; fm < 4; ++fm)
#pragma unroll
            for (int fn = 0; fn < 4; ++fn) {
                acc[fm][fn] = __builtin_amdgcn_mfma_f32_16x16x32_bf16(afh[fm], bfh[fn], acc[fm][fn], 0, 0, 0);
                acc[fm][fn] = __builtin_amdgcn_mfma_f32_16x16x32_bf16(afh[fm], bfl[fn], acc[fm][fn], 0, 0, 0);
                acc[fm][fn] = __builtin_amdgcn_mfma_f32_16x16x32_bf16(afl[fm], bfh[fn], acc[fm][fn], 0, 0, 0);
                acc[fm][fn] = __builtin_amdgcn_mfma_f32_16x16x32_bf16(afl[fm], bfl[fn], acc[fm][fn], 0, 0, 0);
            }
        __syncthreads();
    }

#pragma unroll
    for (int fn = 0; fn < 4; ++fn) {
        int n = n0 + wc * 64 + fn * 16 + l15;
        int h = n >> 6, dh = n & 63;
#pragma unroll
        for (int fm = 0; fm < 4; ++fm) {
#pragma unroll
            for (int q = 0; q < 4; ++q) {
                int m = m0 + wr * 64 + fm * 16 + lq * 4 + q;
                int bb = m >> 12, s = m & 4095;
                out[((((size_t)bb * H_ + h) * S_ + s) << 6) + dh] = acc[fm][fn][q];
            }
        }
    }
}

// ---------------------------------------------------------------------------
// bf16 MFMA GEMM, 128x128 tile, BK=32, 4 waves x (64x64 quadrant).
// MODE 0: out bf16 head-layout                       (v = x2 @ Wv)
// MODE 1: out fp32 = resid + sigf(gate[n]) * acc     (y1)
// MODE 2: out bf16 = relu(acc + bias[n])             (t)
// MODE 3: out fp32 = resid + sigf(gate[n])*(acc+bias)(y2)
// ---------------------------------------------------------------------------
template<int MODE>
__global__ __launch_bounds__(256)
void gemm_bf16(const unsigned short* __restrict__ A,
               const unsigned short* __restrict__ BT,
               void* __restrict__ outv,
               const float* __restrict__ bias,
               const float* __restrict__ resid,
               const float* __restrict__ gatev) {
    __shared__ __align__(16) unsigned short Als[128 * 32];
    __shared__ __align__(16) unsigned short Bls[128 * 32];
    const int tid = threadIdx.x;
    const int lane = tid & 63, w = tid >> 6;
    const int wr = w >> 1, wc = w & 1;
    const int m0 = blockIdx.y * 128, n0 = blockIdx.x * 128;
    const int l15 = lane & 15, l4 = lane >> 4;

    f32x4 acc[4][4];
#pragma unroll
    for (int i = 0; i < 4; ++i)
#pragma unroll
        for (int j = 0; j < 4; ++j) acc[i][j] = (f32x4)0.f;

    for (int kt = 0; kt < 1024; kt += 32) {
#pragma unroll
        for (int i = 0; i < 2; ++i) {
            int d = i * 256 + tid;
            int r = d >> 2, sl = d & 3;
            gload_lds16(&A [(size_t)(m0 + r) * 1024 + kt + sl * 8], &Als[(size_t)d * 8]);
            gload_lds16(&BT[(size_t)(n0 + r) * 1024 + kt + sl * 8], &Bls[(size_t)d * 8]);
        }
        __syncthreads();
        bf16x8 af[4], bfr[4];
#pragma unroll
        for (int f = 0; f < 4; ++f) {
            af[f]  = *reinterpret_cast<const bf16x8*>(&Als[(size_t)(wr * 64 + f * 16 + l15) * 32 + l4 * 8]);
            bfr[f] = *reinterpret_cast<const bf16x8*>(&Bls[(size_t)(wc * 64 + f * 16 + l15) * 32 + l4 * 8]);
        }
#pragma unroll
        for (int fm = 0; fm < 4; ++fm)
#pragma unroll
            for (int fn = 0; fn < 4; ++fn)
                acc[fm][fn] = __builtin_amdgcn_mfma_f32_16x16x32_bf16(af[fm], bfr[fn], acc[fm][fn], 0, 0, 0);
        __syncthreads();
    }

#pragma unroll
    for (int fn = 0; fn < 4; ++fn) {
        int n = n0 + wc * 64 + fn * 16 + l15;
        float sg = 0.f, bs = 0.f;
        if (MODE == 1) sg = sigf(gatev[n]);
        if (MODE == 2) bs = bias[n];
        if (MODE == 3) { sg = sigf(gatev[n]); bs = bias[n]; }
#pragma unroll
        for (int fm = 0; fm < 4; ++fm) {
#pragma unroll
            for (int q = 0; q < 4; ++q) {
                int m = m0 + wr * 64 + fm * 16 + l4 * 4 + q;
                float v = acc[fm][fn][q];
                if (MODE == 0) {
                    int bb = m >> 12, s = m & 4095;
                    int h = n >> 6, dh = n & 63;
                    ((unsigned short*)outv)[((((size_t)bb * H_ + h) * S_ + s) << 6) + dh] = f2bf(v);
                } else if (MODE == 1) {
                    size_t idx = (size_t)m * 1024 + n;
                    ((float*)outv)[idx] = resid[idx] + sg * v;
                } else if (MODE == 2) {
                    ((unsigned short*)outv)[(size_t)m * 1024 + n] = f2bf(fmaxf(v + bs, 0.f));
                } else {
                    size_t idx = (size_t)m * 1024 + n;
                    ((float*)outv)[idx] = resid[idx] + sg * (v + bs);
                }
            }
        }
    }
}

// ---------------------------------------------------------------------------
// fp32 -> bf16 elementwise (x2 copy)
// ---------------------------------------------------------------------------
__global__ __launch_bounds__(256)
void f2bf_kernel(const float* __restrict__ in, unsigned short* __restrict__ out) {
    size_t i = ((size_t)blockIdx.x * 256 + threadIdx.x) * 8;
    float4 a = *reinterpret_cast<const float4*>(&in[i]);
    float4 b = *reinterpret_cast<const float4*>(&in[i + 4]);
    ushort8 o;
    o[0] = f2bf(a.x); o[1] = f2bf(a.y); o[2] = f2bf(a.z); o[3] = f2bf(a.w);
    o[4] = f2bf(b.x); o[5] = f2bf(b.y); o[6] = f2bf(b.z); o[7] = f2bf(b.w);
    *reinterpret_cast<ushort8*>(&out[i]) = o;
}

// ---------------------------------------------------------------------------
// Weight transpose + convert: W(K,N) f32 -> WT(N,K) bf16
// ---------------------------------------------------------------------------
__global__ __launch_bounds__(256)
void wtrans_kernel(const float* __restrict__ W, unsigned short* __restrict__ WT) {
    __shared__ float tile[32][33];
    int n0 = blockIdx.x * 32, k0 = blockIdx.y * 32;
    int lx = threadIdx.x & 31, ly = threadIdx.x >> 5;
#pragma unroll
    for (int i = 0; i < 4; ++i)
        tile[ly + i * 8][lx] = W[(size_t)(k0 + ly + i * 8) * 1024 + n0 + lx];
    __syncthreads();
#pragma unroll
    for (int i = 0; i < 4; ++i)
        WT[(size_t)(n0 + ly + i * 8) * 1024 + k0 + lx] = f2bf(tile[lx][ly + i * 8]);
}

// ---------------------------------------------------------------------------
// Weight transpose + hi/lo split: W(K,N) f32 -> WThi/WTlo (N,K) bf16
// hi = trunc16(x); lo = rne_bf16(x - hi)  (matches gemm_qk_split convention)
// ---------------------------------------------------------------------------
__global__ __launch_bounds__(256)
void wtrans_split(const float* __restrict__ W,
                  unsigned short* __restrict__ WThi,
                  unsigned short* __restrict__ WTlo) {
    __shared__ float tile[32][33];
    int n0 = blockIdx.x * 32, k0 = blockIdx.y * 32;
    int lx = threadIdx.x & 31, ly = threadIdx.x >> 5;
#pragma unroll
    for (int i = 0; i < 4; ++i)
        tile[ly + i * 8][lx] = W[(size_t)(k0 + ly + i * 8) * 1024 + n0 + lx];
    __syncthreads();
#pragma unroll
    for (int i = 0; i < 4; ++i) {
        float x = tile[lx][ly + i * 8];
        union { float f; unsigned u; } vv; vv.f = x;
        size_t idx = (size_t)(n0 + ly + i * 8) * 1024 + k0 + lx;
        WThi[idx] = (unsigned short)(vv.u >> 16);
        union { unsigned u; float f; } hb; hb.u = vv.u & 0xFFFF0000u;
        WTlo[idx] = f2bf(x - hb.f);
    }
}

// ---------------------------------------------------------------------------
// stage: per row, qnorm[row] = |q|, qb = bf16(q) (head layout). Wave per row.
// ---------------------------------------------------------------------------
__global__ __launch_bounds__(256)
void stage_kernel(const float* __restrict__ qk, unsigned short* __restrict__ qb,
                  float* __restrict__ qnorm) {
    int tid = threadIdx.x, wv = tid >> 6, lane = tid & 63;
    int row = blockIdx.x * 4 + wv;
    float q = qk[(size_t)row * 64 + lane];
    float ss = q * q;
#pragma unroll
    for (int off = 32; off; off >>= 1) ss += __shfl_xor(ss, off);
    if (lane == 0) qnorm[row] = sqrtf(ss);
    qb[(size_t)row * 64 + lane] = f2bf(q);
}

// ---------------------------------------------------------------------------
// buckets: rot slice staged in LDS (8 KB), broadcast float4 reads.
// ---------------------------------------------------------------------------
__global__ __launch_bounds__(256)
void buckets_kernel(const float* __restrict__ qk, const float* __restrict__ rot,
                    int* __restrict__ buckets) {
    __shared__ __align__(16) float rs[64][32];   // [d][m], 8 KB
    int g = blockIdx.y;                  // (b*H+h)*4 + r, 0..127
    int r = g & 3;
    int bh = g >> 2;
    int h = bh & 15;
    const float* rbase = rot + (size_t)(h * NH_ + r) * 64 * 32;
    for (int i = threadIdx.x; i < 512; i += 256)
        *reinterpret_cast<float4*>(&rs[0][0] + (size_t)i * 4) =
            *reinterpret_cast<const float4*>(rbase + (size_t)i * 4);
    __syncthreads();

    int tok = blockIdx.x * 256 + threadIdx.x;
    const float* qrow = qk + ((size_t)bh * S_ + tok) * 64;

    float rotd[32];
#pragma unroll
    for (int m = 0; m < 32; ++m) rotd[m] = 0.f;
#pragma unroll
    for (int d4 = 0; d4 < 16; ++d4) {
        float4 q4 = *reinterpret_cast<const float4*>(qrow + (d4 << 2));
#pragma unroll
        for (int mm = 0; mm < 8; ++mm) {
            float4 r0 = *reinterpret_cast<const float4*>(&rs[d4 * 4 + 0][mm * 4]);
            float4 r1 = *reinterpret_cast<const float4*>(&rs[d4 * 4 + 1][mm * 4]);
            float4 r2 = *reinterpret_cast<const float4*>(&rs[d4 * 4 + 2][mm * 4]);
            float4 r3 = *reinterpret_cast<const float4*>(&rs[d4 * 4 + 3][mm * 4]);
            rotd[mm * 4 + 0] += q4.x * r0.x + q4.y * r1.x + q4.z * r2.x + q4.w * r3.x;
            rotd[mm * 4 + 1] += q4.x * r0.y + q4.y * r1.y + q4.z * r2.y + q4.w * r3.y;
            rotd[mm * 4 + 2] += q4.x * r0.z + q4.y * r1.z + q4.z * r2.z + q4.w * r3.z;
            rotd[mm * 4 + 3] += q4.x * r0.w + q4.y * r1.w + q4.z * r2.w + q4.w * r3.w;
        }
    }
    float bv = rotd[0]; int bi = 0;
#pragma unroll
    for (int m = 1; m < 32; ++m) if (rotd[m] > bv) { bv = rotd[m]; bi = m; }
#pragma unroll
    for (int m = 0; m < 32; ++m) { float nv = -rotd[m]; if (nv > bv) { bv = nv; bi = 32 + m; } }
    buckets[(size_t)g * S_ + tok] = bi;
}

// ---------------------------------------------------------------------------
// Stable counting sort per group g: perm = argsort(bucket*S + pos)
// ---------------------------------------------------------------------------
__global__ __launch_bounds__(256)
void sort_kernel(const int* __restrict__ buckets, int* __restrict__ perm) {
    __shared__ int bk[4096];
    __shared__ int qcnt[4][64];
    __shared__ int qoff[4][64];
    __shared__ int ps[4096];
    int g = blockIdx.x, tid = threadIdx.x;
    const int* bp = buckets + (size_t)g * S_;
    for (int i = 0; i < 16; ++i) bk[tid + 256 * i] = bp[tid + 256 * i];
    qcnt[tid >> 6][tid & 63] = 0;
    __syncthreads();
    int q = tid >> 6, l = tid & 63;
    for (int i = 0; i < 16; ++i) {
        int pos = q * 1024 + l + 64 * i;
        atomicAdd(&qcnt[q][bk[pos]], 1);
    }
    __syncthreads();
    if (tid == 0) {
        int run = 0;
        for (int b = 0; b < 64; ++b)
            for (int qq = 0; qq < 4; ++qq) { qoff[qq][b] = run; run += qcnt[qq][b]; }
    }
    __syncthreads();
    {
        int base = qoff[q][l], cnt = 0;
        for (int j = q * 1024; j < q * 1024 + 1024; ++j) {
            if (bk[j] == l) { ps[base + cnt] = j; ++cnt; }
        }
    }
    __syncthreads();
    int* pp = perm + (size_t)g * S_;
    for (int i = 0; i < 16; ++i) pp[tid + 256 * i] = ps[tid + 256 * i];
}

// ---------------------------------------------------------------------------
// FUSED LSH attention: per (g, chunk): MFMA dots (bf16), p = exp(dots - M_t),
// atomic D += rowsum(p), O = P@V via MFMA, atomic U += O.
// ---------------------------------------------------------------------------
__global__ __launch_bounds__(256)
void fused_attn(const unsigned short* __restrict__ qb,
                const unsigned short* __restrict__ vb,
                const int* __restrict__ perm,
                const float* __restrict__ qnorm,
                float* __restrict__ U, float* __restrict__ Dbuf) {
    __shared__ __align__(16) char smem[34816];
    unsigned short (*Ks)[72]  = (unsigned short (*)[72])smem;
    unsigned short (*P)[136]  = (unsigned short (*)[136])smem;
    unsigned short (*Vt)[136] = (unsigned short (*)[136])(smem + 17408);
    __shared__ int   toks[128];
    __shared__ float rk[128];
    __shared__ float qn_s[64];

    const int tid = threadIdx.x;
    const int g = blockIdx.y, c = blockIdx.x;
    const int bh = g >> 2;
    const int pc = (c + 63) & 63;
    const size_t gS = (size_t)g * S_, bhS = (size_t)bh * S_;

    if (tid < 128) {
        toks[tid] = (tid < 64) ? perm[gS + c * 64 + tid]
                               : perm[gS + pc * 64 + (tid - 64)];
    }
    __syncthreads();
    if (tid < 128) {
        float qn = qnorm[bhS + toks[tid]];
        rk[tid] = SCALE_ / (qn + 1e-6f);
        if (tid < 64) qn_s[tid] = SCALE_ * qn;
    }
#pragma unroll
    for (int i = 0; i < 4; ++i) {
        int cc = tid + 256 * i;
        int row = cc >> 3, sub = cc & 7;
        ushort8 v = *reinterpret_cast<const ushort8*>(&qb[(bhS + toks[row]) * 64 + sub * 8]);
        *reinterpret_cast<ushort8*>(&Ks[row][sub * 8]) = v;
    }
    __syncthreads();

    const int lane = tid & 63, w = tid >> 6;
    const int l15 = lane & 15, l4 = lane >> 4;

    f32x4 accd[8];
#pragma unroll
    for (int fn = 0; fn < 8; ++fn) accd[fn] = (f32x4)0.f;
#pragma unroll
    for (int ks = 0; ks < 2; ++ks) {
        bf16x8 a = *reinterpret_cast<const bf16x8*>(&Ks[w * 16 + l15][l4 * 8 + ks * 32]);
#pragma unroll
        for (int fn = 0; fn < 8; ++fn) {
            bf16x8 b = *reinterpret_cast<const bf16x8*>(&Ks[fn * 16 + l15][l4 * 8 + ks * 32]);
            accd[fn] = __builtin_amdgcn_mfma_f32_16x16x32_bf16(a, b, accd[fn], 0, 0, 0);
        }
    }
    __syncthreads();

    float dsum[4] = {0.f, 0.f, 0.f, 0.f};
#pragma unroll
    for (int fn = 0; fn < 8; ++fn) {
        int j = fn * 16 + l15;
        float rj = rk[j];
#pragma unroll
        for (int q = 0; q < 4; ++q) {
            int i = w * 16 + l4 * 4 + q;
            float p = __expf(accd[fn][q] * rj - qn_s[i]);
            dsum[q] += p;
            P[i][j] = f2bf(p);
        }
    }
#pragma unroll
    for (int q = 0; q < 4; ++q) {
#pragma unroll
        for (int off = 1; off < 16; off <<= 1) dsum[q] += __shfl_xor(dsum[q], off);
    }
    if (l15 == 0) {
#pragma unroll
        for (int q = 0; q < 4; ++q)
            atomicAdd(&Dbuf[bhS + toks[w * 16 + l4 * 4 + q]], dsum[q]);
    }
#pragma unroll
    for (int i = 0; i < 4; ++i) {
        int cc = tid + 256 * i;
        int row = cc >> 3, sub = cc & 7;
        ushort8 v = *reinterpret_cast<const ushort8*>(&vb[(bhS + toks[row]) * 64 + sub * 8]);
#pragma unroll
        for (int e = 0; e < 8; ++e) Vt[sub * 8 + e][row] = v[e];
    }
    __syncthreads();

    f32x4 acco[4];
#pragma unroll
    for (int fn = 0; fn < 4; ++fn) acco[fn] = (f32x4)0.f;
#pragma unroll
    for (int ks = 0; ks < 4; ++ks) {
        bf16x8 a = *reinterpret_cast<const bf16x8*>(&P[w * 16 + l15][l4 * 8 + ks * 32]);
#pragma unroll
        for (int fn = 0; fn < 4; ++fn) {
            bf16x8 b = *reinterpret_cast<const bf16x8*>(&Vt[fn * 16 + l15][l4 * 8 + ks * 32]);
            acco[fn] = __builtin_amdgcn_mfma_f32_16x16x32_bf16(a, b, acco[fn], 0, 0, 0);
        }
    }
#pragma unroll
    for (int fn = 0; fn < 4; ++fn) {
        int dh = fn * 16 + l15;
#pragma unroll
        for (int q = 0; q < 4; ++q) {
            int i = w * 16 + l4 * 4 + q;
            atomicAdd(&U[(bhS + toks[i]) * 64 + dh], acco[fn][q]);
        }
    }
}

// ---------------------------------------------------------------------------
// Local window attention + gate + mix. bf16 q/v inputs; lsh = U/D.
// ---------------------------------------------------------------------------
__global__ __launch_bounds__(256)
void mix_kernel(const unsigned short* __restrict__ qb, const float* __restrict__ qnorm,
                const unsigned short* __restrict__ vb,
                const float* __restrict__ U, const float* __restrict__ Dbuf,
                const float* __restrict__ w_gate, const float* __restrict__ b_gate,
                unsigned short* __restrict__ mixb, float* __restrict__ gpart) {
    __shared__ float gacc[4];
    int tid = threadIdx.x, wv = tid >> 6, lane = tid & 63;
    int row = blockIdx.x * 4 + wv;       // bh*S + s
    int s = row & (S_ - 1);
    int bh = row >> 12;
    int h = bh & 15, b = bh >> 4;
    float qd = bf2f(qb[(size_t)row * 64 + lane]);
    float pw[9], vbv[9];
#pragma unroll
    for (int w = 0; w < 9; ++w) {
        int idx = s - 4 + w;
        bool valid = (idx >= 0) && (idx < S_);
        int ic = idx < 0 ? 0 : (idx >= S_ ? S_ - 1 : idx);
        size_t rr = (size_t)bh * S_ + ic;
        float kk = bf2f(qb[rr * 64 + lane]);
        float p = qd * kk;
#pragma unroll
        for (int off = 32; off; off >>= 1) p += __shfl_xor(p, off);
        float rn = 1.f / (qnorm[rr] + 1e-6f);
        pw[w] = valid ? p * rn * SCALE_ : -1e9f;
        vbv[w] = bf2f(vb[rr * 64 + lane]);
    }
    float mx = pw[0];
#pragma unroll
    for (int w = 1; w < 9; ++w) mx = fmaxf(mx, pw[w]);
    float den = 0.f, loc = 0.f;
#pragma unroll
    for (int w = 0; w < 9; ++w) { float e = __expf(pw[w] - mx); den += e; loc += e * vbv[w]; }
    loc /= den;
    float gv = qd * w_gate[h * 64 + lane];
#pragma unroll
    for (int off = 32; off; off >>= 1) gv += __shfl_xor(gv, off);
    float gg = sigf(gv + b_gate[h]);
    float lv = U[(size_t)row * 64 + lane] / Dbuf[row];
    float mval = gg * loc + (1.f - gg) * lv;
    mixb[((size_t)b * S_ + s) * 1024 + h * 64 + lane] = f2bf(mval);
    if (lane == 0) gacc[wv] = gg * (1.f - gg);
    __syncthreads();
    if (tid == 0) gpart[blockIdx.x] = gacc[0] + gacc[1] + gacc[2] + gacc[3];
}

__global__ __launch_bounds__(256)
void reg_reduce(const float* __restrict__ gpart, float* __restrict__ outreg) {
    __shared__ float part[4];
    float sm = 0.f;
    for (int i = threadIdx.x; i < 32768; i += 256) sm += gpart[i];
#pragma unroll
    for (int off = 32; off; off >>= 1) sm += __shfl_xor(sm, off);
    if ((threadIdx.x & 63) == 0) part[threadIdx.x >> 6] = sm;
    __syncthreads();
    if (threadIdx.x == 0) outreg[0] = (part[0] + part[1] + part[2] + part[3]) * (1.f / 131072.f);
}

// ---------------------------------------------------------------------------
// LayerNorm over D=1024, block per row; bf16 out
// ---------------------------------------------------------------------------
__global__ __launch_bounds__(256)
void ln_kernel(const float* __restrict__ x, const float* __restrict__ gg,
               const float* __restrict__ bb, unsigned short* __restrict__ outp) {
    __shared__ float ps[4][2];
    int row = blockIdx.x, tid = threadIdx.x;
    int wv = tid >> 6, lane = tid & 63;
    const float* xr = x + (size_t)row * 1024;
    float4 xv = *reinterpret_cast<const float4*>(&xr[tid * 4]);
    float s = xv.x + xv.y + xv.z + xv.w;
    float s2 = xv.x * xv.x + xv.y * xv.y + xv.z * xv.z + xv.w * xv.w;
#pragma unroll
    for (int off = 32; off; off >>= 1) { s += __shfl_xor(s, off); s2 += __shfl_xor(s2, off); }
    if (lane == 0) { ps[wv][0] = s; ps[wv][1] = s2; }
    __syncthreads();
    s  = ps[0][0] + ps[1][0] + ps[2][0] + ps[3][0];
    s2 = ps[0][1] + ps[1][1] + ps[2][1] + ps[3][1];
    float mean = s * (1.f / 1024.f);
    float var = s2 * (1.f / 1024.f) - mean * mean;
    float rs = rsqrtf(var + 1e-5f);
    float4 gv = *reinterpret_cast<const float4*>(&gg[tid * 4]);
    float4 bv = *reinterpret_cast<const float4*>(&bb[tid * 4]);
    ushort4v o;
    o[0] = f2bf((xv.x - mean) * rs * gv.x + bv.x);
    o[1] = f2bf((xv.y - mean) * rs * gv.y + bv.y);
    o[2] = f2bf((xv.z - mean) * rs * gv.z + bv.z);
    o[3] = f2bf((xv.w - mean) * rs * gv.w + bv.w);
    *reinterpret_cast<ushort4v*>(&outp[(size_t)row * 1024 + tid * 4]) = o;
}

// ---------------------------------------------------------------------------
// ws layout (59.1 MB envelope, unchanged from round 5):
//  A 0:        x2b -> qb -> tb           (16.8 MB)
//  B 16777216: v_bf16 -> hb              (16.8 MB)
//  C 33554432: WqkThi(2MB)+WqkTlo(2MB) [dead before buckets]
//              -> buckets (2MB) -> mixb (16.8 MB)   [sequential lifetimes]
//  D 50331648: WvT/WoT/W1T/W2T           (4 x 2 MB)
//  E 58720256: perm                      (2 MB)
//  F 60817408: qnorm                     (0.5 MB)
//  G 61341696: Dbuf                      (0.5 MB)
//  H 61865984: gpart                     (128 KB)
// d_out: [0] qk -> y1; [BSD] U-accum -> y2; [2BSD] reg
// ---------------------------------------------------------------------------
extern "C" void kernel_launch(void* const* d_in, const int* in_sizes, int n_in,
                              void* d_out, int out_size, void* d_ws, size_t ws_size,
                              hipStream_t stream) {
    (void)in_sizes; (void)n_in; (void)out_size; (void)ws_size;
    const float* x1    = (const float*)d_in[0];
    const float* x2    = (const float*)d_in[1];
    const float* Wqk   = (const float*)d_in[2];
    const float* Wv    = (const float*)d_in[3];
    const float* Wo    = (const float*)d_in[4];
    const float* rot   = (const float*)d_in[5];
    const float* w_gate= (const float*)d_in[6];
    const float* b_gate= (const float*)d_in[7];
    const float* ln_g  = (const float*)d_in[8];
    const float* ln_b  = (const float*)d_in[9];
    const float* W1    = (const float*)d_in[10];
    const float* b1    = (const float*)d_in[11];
    const float* W2    = (const float*)d_in[12];
    const float* b2    = (const float*)d_in[13];
    const float* alpha = (const float*)d_in[14];
    const float* beta  = (const float*)d_in[15];

    float* out = (float*)d_out;
    float* qk  = out;                       // -> y1
    float* Ubuf= out + (size_t)BSD_;        // -> y2
    float* y1  = out;
    float* y2  = out + (size_t)BSD_;

    char* ws = (char*)d_ws;
    unsigned short* x2b   = (unsigned short*)(ws + 0);
    unsigned short* qb    = (unsigned short*)(ws + 0);
    unsigned short* tb    = (unsigned short*)(ws + 0);
    unsigned short* vbuf  = (unsigned short*)(ws + 16777216);
    unsigned short* hb    = (unsigned short*)(ws + 16777216);
    unsigned short* WqkTh = (unsigned short*)(ws + 33554432);   // dead before buckets
    unsigned short* WqkTl = (unsigned short*)(ws + 35651584);
    int*   buckets        = (int*)  (ws + 33554432);
    unsigned short* mixb  = (unsigned short*)(ws + 33554432);
    unsigned short* WvT   = (unsigned short*)(ws + 50331648);
    unsigned short* WoT   = (unsigned short*)(ws + 52428800);
    unsigned short* W1T   = (unsigned short*)(ws + 54525952);
    unsigned short* W2T   = (unsigned short*)(ws + 56623104);
    int*   perm           = (int*)  (ws + 58720256);
    float* qnorm          = (float*)(ws + 60817408);
    float* Dbuf           = (float*)(ws + 61341696);
    float* gpart          = (float*)(ws + 61865984);

    hipMemsetAsync(Ubuf, 0, (size_t)BSD_ * sizeof(float), stream);
    hipMemsetAsync(Dbuf, 0, 131072 * sizeof(float), stream);

    dim3 gg(8, 64), gb(256);
    f2bf_kernel<<<4096, 256, 0, stream>>>(x2, x2b);
    wtrans_split<<<dim3(32, 32), 256, 0, stream>>>(Wqk, WqkTh, WqkTl);
    wtrans_kernel<<<dim3(32, 32), 256, 0, stream>>>(Wv, WvT);
    wtrans_kernel<<<dim3(32, 32), 256, 0, stream>>>(Wo, WoT);
    wtrans_kernel<<<dim3(32, 32), 256, 0, stream>>>(W1, W1T);
    wtrans_kernel<<<dim3(32, 32), 256, 0, stream>>>(W2, W2T);

    // qk = x2 @ Wqk  (split-bf16, near-fp32; feeds bucket argmax)
    gemm_qk_split<<<gg, gb, 0, stream>>>(x2, WqkTh, WqkTl, qk);
    gemm_bf16<0><<<gg, gb, 0, stream>>>(x2b, WvT, vbuf, nullptr, nullptr, nullptr);

    stage_kernel<<<32768, 256, 0, stream>>>(qk, qb, qnorm);
    buckets_kernel<<<dim3(16, 128), 256, 0, stream>>>(qk, rot, buckets);
    sort_kernel<<<128, 256, 0, stream>>>(buckets, perm);

    fused_attn<<<dim3(64, 128), 256, 0, stream>>>(qb, vbuf, perm, qnorm, Ubuf, Dbuf);

    mix_kernel<<<32768, 256, 0, stream>>>(qb, qnorm, vbuf, Ubuf, Dbuf,
                                          w_gate, b_gate, mixb, gpart);
    reg_reduce<<<1, 256, 0, stream>>>(gpart, out + 2 * (size_t)BSD_);

    gemm_bf16<1><<<gg, gb, 0, stream>>>(mixb, WoT, y1, nullptr, x1, alpha);
    ln_kernel<<<8192, 256, 0, stream>>>(y1, ln_g, ln_b, hb);
    gemm_bf16<2><<<gg, gb, 0, stream>>>(hb, W1T, tb, b1, nullptr, nullptr);
    gemm_bf16<3><<<gg, gb, 0, stream>>>(tb, W2T, y2, b2, x2, beta);
}